// Round 10
// baseline (398.291 us; speedup 1.0000x reference)
//
#include <hip/hip_runtime.h>

typedef unsigned short u16;
typedef __bf16 bf16x8 __attribute__((ext_vector_type(8)));
typedef float f32x4 __attribute__((ext_vector_type(4)));

#define HN 128
#define TM 64
#define LTM 32        // layer-kernel tile (32 nodes/block, 938 blocks)
#define ASTRIDE 136   // 128 + 8 pad (u16), rows 16B-aligned

__device__ __forceinline__ u16 f2bf(float f) {
  union { float f; unsigned u; } v; v.f = f;
  unsigned r = v.u + 0x7fffu + ((v.u >> 16) & 1u);
  return (u16)(r >> 16);
}
__device__ __forceinline__ float bf2f(u16 v) {
  union { unsigned u; float f; } x; x.u = ((unsigned)v) << 16; return x.f;
}
__device__ __forceinline__ float bflo(unsigned v) {
  union { unsigned u; float f; } x; x.u = v << 16; return x.f;
}
__device__ __forceinline__ float bfhi(unsigned v) {
  union { unsigned u; float f; } x; x.u = v & 0xffff0000u; return x.f;
}
// fast silu: x * rcp(1 + exp2(-log2e*x)) — v_exp_f32/v_rcp_f32, ~1 ulp
__device__ __forceinline__ float silu_f(float x) {
  float e = __builtin_amdgcn_exp2f(-1.442695041f * x);
  return x * __builtin_amdgcn_rcpf(1.f + e);
}

// ---- pack weights into MFMA B-fragment layout: P[kg][n][8], kg=k/8 ----
// mats per layer: 0=msgW1a 1=msgW1b 2=msgW2 3=nodeW1a 4=nodeW1b 5=nodeW2
// Also zeroes deg[N] and g[G*HN].
__global__ void pack_weights(const float* __restrict__ msg_w1, const float* __restrict__ msg_w2,
                             const float* __restrict__ node_w1, const float* __restrict__ node_w2,
                             u16* __restrict__ pw, int* __restrict__ deg,
                             float* __restrict__ g, int N_, int GH) {
  int id = blockIdx.x * 256 + threadIdx.x;
  if (id < N_) deg[id] = 0;
  if (id < GH) g[id] = 0.f;
  if (id >= 4 * 6 * 16384) return;
  int l = id / (6 * 16384);
  int rem = id % (6 * 16384);
  int m = rem / 16384;
  int e = rem % 16384;
  int kg = e >> 10;
  int n = (e >> 3) & 127;
  int j = e & 7;
  int k = kg * 8 + j;
  float v = 0.f;
  switch (m) {
    case 0: v = msg_w1[(l * 257 + k) * 128 + n]; break;
    case 1: v = msg_w1[(l * 257 + 128 + k) * 128 + n]; break;
    case 2: v = msg_w2[(l * 128 + k) * 128 + n]; break;
    case 3: v = node_w1[(l * 256 + k) * 128 + n]; break;
    case 4: v = node_w1[(l * 256 + 128 + k) * 128 + n]; break;
    case 5: v = node_w2[(l * 128 + k) * 128 + n]; break;
  }
  pw[id] = f2bf(v);
}

// A from LDS band (rows w*16..w*16+15), B from LDS (64-row tile kernels)
__device__ __forceinline__ void gemm64(const u16* s_A, const u16* s_W,
                                       int w, int quad, int m16, f32x4 acc[8]) {
#pragma unroll
  for (int ks = 0; ks < 4; ks++) {
    bf16x8 a = *(const bf16x8*)&s_A[(w * 16 + m16) * ASTRIDE + ks * 32 + quad * 8];
#pragma unroll
    for (int ct = 0; ct < 8; ct++) {
      bf16x8 b = *(const bf16x8*)&s_W[(ks * 4 + quad) * 1024 + (ct * 16 + m16) * 8];
      acc[ct] = __builtin_amdgcn_mfma_f32_16x16x32_bf16(a, b, acc[ct], 0, 0, 0);
    }
  }
}

// eighth-gemm: A rows rh*16.., B col-quarter ch (cols (ch*2+ct)*16); B from L2
__device__ __forceinline__ void gemm32q_gb(const u16* s_A, const u16* __restrict__ gW,
                                           int rh, int ch, int quad, int m16, f32x4 acc[2]) {
#pragma unroll
  for (int ks = 0; ks < 4; ks++) {
    bf16x8 a = *(const bf16x8*)&s_A[(rh * 16 + m16) * ASTRIDE + ks * 32 + quad * 8];
#pragma unroll
    for (int ct = 0; ct < 2; ct++) {
      bf16x8 b = *(const bf16x8*)&gW[(ks * 4 + quad) * 1024 + ((ch * 2 + ct) * 16 + m16) * 8];
      acc[ct] = __builtin_amdgcn_mfma_f32_16x16x32_bf16(a, b, acc[ct], 0, 0, 0);
    }
  }
}

// eighth-gemm, A from registers
__device__ __forceinline__ void gemm32q_ra_gb(const bf16x8 aH[4], const u16* __restrict__ gW,
                                              int ch, int quad, int m16, f32x4 acc[2]) {
#pragma unroll
  for (int ks = 0; ks < 4; ks++) {
#pragma unroll
    for (int ct = 0; ct < 2; ct++) {
      bf16x8 b = *(const bf16x8*)&gW[(ks * 4 + quad) * 1024 + ((ch * 2 + ct) * 16 + m16) * 8];
      acc[ct] = __builtin_amdgcn_mfma_f32_16x16x32_bf16(aH[ks], b, acc[ct], 0, 0, 0);
    }
  }
}

// ---- fold: Wc = msgW2 @ nodeW1b (bf16, B-frag packed), vc = msg_b2 @ nodeW1b.
// Block (l=0,half=1) also computes layer-0 rank-1 vectors:
//   uv = [uP | vP+vQ+b1 | uQ], uP=emb_w@msgW1a etc. ----
__global__ __launch_bounds__(256) void fold_kernel(
    const float* __restrict__ msg_w2, const float* __restrict__ node_w1,
    const float* __restrict__ msg_b2, const u16* __restrict__ pw,
    u16* __restrict__ pwc, float* __restrict__ vc,
    const float* __restrict__ msg_w1, const float* __restrict__ emb_w,
    const float* __restrict__ emb_b, const float* __restrict__ msg_b1,
    float* __restrict__ uv) {
  __shared__ __align__(16) u16 s_A[TM * ASTRIDE];
  __shared__ __align__(16) u16 s_W[16384];
  const int t = threadIdx.x;
  const int w = t >> 6, lane = t & 63, quad = lane >> 4, m16 = lane & 15;
  const int b = blockIdx.x, l = b >> 1, half = b & 1;
  const int tile0 = half * 64;

  {
    int r = t >> 2, qo = (t & 3) * 32;
    const float4* src = (const float4*)(msg_w2 + (size_t)(l * 128 + tile0 + r) * 128 + qo);
    u16* dst = s_A + r * ASTRIDE + qo;
#pragma unroll
    for (int i = 0; i < 8; i++) {
      float4 v = src[i];
      ushort4 o;
      o.x = f2bf(v.x); o.y = f2bf(v.y); o.z = f2bf(v.z); o.w = f2bf(v.w);
      *(ushort4*)(dst + i * 4) = o;
    }
  }
  {
    const int4* src = (const int4*)(pw + (size_t)(l * 6 + 4) * 16384);
    int4* dst = (int4*)s_W;
#pragma unroll
    for (int i = 0; i < 8; i++) dst[t + i * 256] = src[t + i * 256];
  }
  __syncthreads();
  f32x4 acc[8];
#pragma unroll
  for (int ct = 0; ct < 8; ct++) acc[ct] = {0.f, 0.f, 0.f, 0.f};
  gemm64(s_A, s_W, w, quad, m16, acc);
#pragma unroll
  for (int ct = 0; ct < 8; ct++)
#pragma unroll
    for (int j = 0; j < 4; j++) {
      int k = tile0 + w * 16 + quad * 4 + j;
      int n = ct * 16 + m16;
      pwc[(size_t)l * 16384 + (k >> 3) * 1024 + n * 8 + (k & 7)] = f2bf(acc[ct][j]);
    }
  if (half == 0 && t < 128) {
    float s = 0.f;
    for (int np = 0; np < 128; np++)
      s += msg_b2[l * 128 + np] * node_w1[(size_t)(l * 256 + 128 + np) * 128 + t];
    vc[l * 128 + t] = s;
  }
  if (l == 0 && half == 1 && t < 128) {
    float up = 0.f, vp = 0.f, uq = 0.f, vq = 0.f;
    for (int k = 0; k < 128; k++) {
      float wa = msg_w1[(size_t)k * 128 + t];          // l=0 msgW1a rows
      float wb = msg_w1[(size_t)(128 + k) * 128 + t];  // l=0 msgW1b rows
      up = fmaf(emb_w[k], wa, up);
      vp = fmaf(emb_b[k], wa, vp);
      uq = fmaf(emb_w[k], wb, uq);
      vq = fmaf(emb_b[k], wb, vq);
    }
    uv[t] = up;
    uv[128 + t] = vp + vq + msg_b1[t];
    uv[256 + t] = uq;
  }
}

// ---- counting sort of edges by target; rank = arrival order per target. ----
__global__ void hist_kernel(const int* __restrict__ eidx, int* __restrict__ deg,
                            int* __restrict__ rnk, int E_) {
  int e = blockIdx.x * 256 + threadIdx.x;
  if (e < E_) rnk[e] = atomicAdd(&deg[eidx[E_ + e]], 1);
}

__global__ void scan1_kernel(const int* __restrict__ deg, int* __restrict__ off,
                             int* __restrict__ bsum, int n) {
  __shared__ int s[256];
  int t = threadIdx.x;
  int i = blockIdx.x * 256 + t;
  int v = (i < n) ? deg[i] : 0;
  s[t] = v;
  for (int d = 1; d < 256; d <<= 1) {
    __syncthreads();
    int x = (t >= d) ? s[t - d] : 0;
    __syncthreads();
    s[t] += x;
  }
  __syncthreads();
  if (i < n) off[i] = s[t] - v;
  if (t == 255) bsum[blockIdx.x] = s[255];
}

__global__ void scan2_kernel(int* __restrict__ bsum, int nb) {
  __shared__ int s[256];
  int t = threadIdx.x;
  int v = (t < nb) ? bsum[t] : 0;
  s[t] = v;
  for (int d = 1; d < 256; d <<= 1) {
    __syncthreads();
    int x = (t >= d) ? s[t - d] : 0;
    __syncthreads();
    s[t] += x;
  }
  __syncthreads();
  if (t < nb) bsum[t] = s[t] - v;  // exclusive block offsets
}

__global__ void scan3_kernel(int* __restrict__ off, const int* __restrict__ bsum, int n) {
  int i = blockIdx.x * 256 + threadIdx.x;
  if (i < n) off[i] += bsum[blockIdx.x];
}

// scatter edges into target-sorted order — NO atomics (rank precomputed).
// es8[p] = (src | tgt<<15, dist_bits): 8 B/edge (N < 2^15).
__global__ void scatter_kernel(const int* __restrict__ eidx, const float* __restrict__ pos,
                               const int* __restrict__ off, const int* __restrict__ rnk,
                               int2* __restrict__ es8, int E_) {
  int e = blockIdx.x * 256 + threadIdx.x;
  if (e >= E_) return;
  int sr = eidx[e], tg = eidx[E_ + e];
  float dx = pos[sr * 3 + 0] - pos[tg * 3 + 0];
  float dy = pos[sr * 3 + 1] - pos[tg * 3 + 1];
  float dz = pos[sr * 3 + 2] - pos[tg * 3 + 2];
  float d = dx * dx + dy * dy + dz * dz;
  int p = off[tg] + rnk[e];
  int2 v;
  v.x = sr | (tg << 15);
  v.y = __float_as_int(d);
  es8[p] = v;
}

// edge step with LDS-accumulator close (all targets are block-local).
// PAD GUARD: tg_s is an SGPR; pads (tg_s<0) skip the VALU body entirely.
__device__ __forceinline__ void edge_step_lds(
    int tg_s, float dd_s, unsigned qv,
    int& cur_s, float& p0, float& p1, float& s0, float& s1,
    const u16* __restrict__ P, float* s_S, int cp,
    float wd0, float wd1, int tile0) {
  if (tg_s < 0) return;  // scalar branch: pad slot
  if (tg_s != cur_s) {   // wave-uniform branch
    if (cur_s >= 0) {
      float* dst = &s_S[(cur_s - tile0) * HN + cp];
      atomicAdd(dst, s0);
      atomicAdd(dst + 1, s1);
    }
    cur_s = tg_s; s0 = 0.f; s1 = 0.f;
    unsigned pv = *(const unsigned*)&P[(size_t)tg_s * HN + cp];
    p0 = bflo(pv); p1 = bfhi(pv);
  }
  float x0 = p0 + bflo(qv) + dd_s * wd0;
  float x1 = p1 + bfhi(qv) + dd_s * wd1;
  s0 += silu_f(x0);
  s1 += silu_f(x1);
}

// rank-1 edge step (layer 0): P/Q replaced by affine functions of x
__device__ __forceinline__ void edge_step_r1(
    int tg_s, float dd_s, float xs,
    int& cur_s, float& p0, float& p1, float& s0, float& s1,
    const float* s_xt, float* s_S, int cp,
    float wd0, float wd1, float uP0, float uP1, float vP0, float vP1,
    float uQ0, float uQ1, int tile0) {
  if (tg_s < 0) return;  // scalar branch: pad slot
  if (tg_s != cur_s) {   // wave-uniform branch
    if (cur_s >= 0) {
      float* dst = &s_S[(cur_s - tile0) * HN + cp];
      atomicAdd(dst, s0);
      atomicAdd(dst + 1, s1);
    }
    cur_s = tg_s; s0 = 0.f; s1 = 0.f;
    float xt = s_xt[tg_s - tile0];
    p0 = fmaf(xt, uP0, vP0);
    p1 = fmaf(xt, uP1, vP1);
  }
  float x0 = fmaf(dd_s, wd0, fmaf(xs, uQ0, p0));
  float x1 = fmaf(dd_s, wd1, fmaf(xs, uQ1, p1));
  s0 += silu_f(x0);
  s1 += silu_f(x1);
}

// ---- FUSED layer kernel, LTM=32, 512 threads (8 waves): 938 blocks ->
// ~29 waves/CU available (2x R7). Phase 1: R7's LDS-staged double-buffered
// pipeline, edge span split 8 ways (~80 edges/wave); pad slots skipped via
// scalar guard (fixes R8's 1.4x work inflation). Phase 2: 32x128 MLP split
// into (row-half rh=w>>2) x (col-quarter ch=w&3), acc[2], 8 MFMA/gemm. ----
template <bool FUSE, bool RANK1>
__global__ __launch_bounds__(512) void layer_kernel(
    const u16* __restrict__ P, const u16* __restrict__ Q,
    const u16* __restrict__ hbf, u16* __restrict__ hout,
    const int* __restrict__ off, const int* __restrict__ deg,
    const float* __restrict__ w1d, const int2* __restrict__ es8,
    const u16* __restrict__ pwc, const float* __restrict__ vc,
    const u16* __restrict__ pwn, const float* __restrict__ b1, const float* __restrict__ b2,
    const u16* __restrict__ pw_next, const float* __restrict__ b1_next,
    u16* __restrict__ Pout, u16* __restrict__ Qout,
    const float* __restrict__ xin, const float* __restrict__ uv,
    const float* __restrict__ emb_w, const float* __restrict__ emb_b,
    int nnodes, int E_) {
  __shared__ float s_S[LTM * HN];                   // 16 KB message accumulators
  __shared__ __align__(16) u16 s_A[LTM * ASTRIDE];  // 8.5 KB: ebuf then A-tile
  __shared__ float s_xt[LTM];                       // x of tile nodes (RANK1)
  const int t = threadIdx.x;
  const int w = t >> 6, lane = t & 63, quad = lane >> 4, m16 = lane & 15;
  const int tile0 = blockIdx.x * LTM;
  const int rh = w >> 2;   // row-half (rows rh*16..rh*16+15)
  const int ch = w & 3;    // col-quarter (cols ch*32..ch*32+31)

  // zero s_S (16KB = 1024 float4); stage x-tile if RANK1
  {
    float4 z = {0.f, 0.f, 0.f, 0.f};
    float4* p4 = (float4*)s_S;
#pragma unroll
    for (int i = 0; i < 2; i++) p4[t + i * 512] = z;
  }
  if constexpr (RANK1) {
    if (t < LTM) {
      int n = tile0 + t;
      s_xt[t] = (n < nnodes) ? xin[n] : 0.f;
    }
  }
  __syncthreads();

  // ================= phase 1: edges (8-way wave split) =================
  const int cp = lane * 2;
  const float2 wdv = *(const float2*)&w1d[cp];
  const float wd0 = wdv.x, wd1 = wdv.y;
  const int e_lo = off[tile0];
  const int e_hi = (tile0 + LTM < nnodes) ? off[tile0 + LTM] : E_;
  const int span = e_hi - e_lo;
  const int wstart = e_lo + (span * w) / 8;
  const int wend = e_lo + (span * (w + 1)) / 8;
  const int total = wend - wstart;
  const int nchunks = (total + 63) >> 6;

  int cur_s = -1;
  float s0 = 0.f, s1 = 0.f, p0 = 0.f, p1 = 0.f;

  if constexpr (RANK1) {
    __shared__ float s_xs[8][2][64];
    const float uP0 = uv[cp], uP1 = uv[cp + 1];
    const float vP0 = uv[128 + cp], vP1 = uv[128 + cp + 1];
    const float uQ0 = uv[256 + cp], uQ1 = uv[256 + cp + 1];
    if (nchunks > 0) {
      int2* ebuf = (int2*)(s_A + (w * 4) * ASTRIDE);  // 1 KB within wave's band
      float* xsb = &s_xs[w][0][0];
      // prologue: chunk 0 (es8 + x[src])
      {
        int e = wstart + lane;
        int2 v;
        if (e < wend) v = es8[e];
        else { v.x = (int)0xFFFF8000; v.y = 0; }
        float xl = xin[v.x & 0x7fff];
        ebuf[lane] = v;
        xsb[lane] = xl;
      }
      asm volatile("s_waitcnt lgkmcnt(0)" ::: "memory");
      int tg[8]; float dd[8]; float xs[8];
#pragma unroll
      for (int j = 0; j < 8; j++) {
        int2 v = ebuf[j];
        tg[j] = v.x >> 15; dd[j] = __int_as_float(v.y);
        xs[j] = xsb[j];
      }

      for (int ci = 0; ci < nchunks; ci++) {
        const int cs = (ci & 1), ns = ((ci + 1) & 1);
        const int2* cb = ebuf + cs * 64;
        const float* cx = xsb + cs * 64;
        const int2* nb = ebuf + ns * 64;
        const float* nx = xsb + ns * 64;
        int2 vnext; vnext.x = (int)0xFFFF8000; vnext.y = 0;
        {
          int e = wstart + (ci + 1) * 64 + lane;
          if (ci + 1 < nchunks && e < wend) vnext = es8[e];
        }
        // groups 0..2 (prefetch g+1 from LDS)
#pragma unroll
        for (int g = 0; g < 3; g++) {
          int tgn[8]; float ddn[8]; float xsn[8];
#pragma unroll
          for (int j = 0; j < 8; j++) {
            int2 v = cb[(g + 1) * 8 + j];
            tgn[j] = v.x >> 15; ddn[j] = __int_as_float(v.y);
            xsn[j] = cx[(g + 1) * 8 + j];
          }
#pragma unroll
          for (int j = 0; j < 8; j++) {
            int tg_s = __builtin_amdgcn_readfirstlane(tg[j]);
            edge_step_r1(tg_s, dd[j], xs[j], cur_s, p0, p1, s0, s1, s_xt, s_S, cp,
                         wd0, wd1, uP0, uP1, vP0, vP1, uQ0, uQ1, tile0);
          }
#pragma unroll
          for (int j = 0; j < 8; j++) { tg[j] = tgn[j]; dd[j] = ddn[j]; xs[j] = xsn[j]; }
        }
        // es8 arrived by now; issue the dependent x gather
        float xnext = xin[vnext.x & 0x7fff];
        // groups 3..6
#pragma unroll
        for (int g = 3; g < 7; g++) {
          int tgn[8]; float ddn[8]; float xsn[8];
#pragma unroll
          for (int j = 0; j < 8; j++) {
            int2 v = cb[(g + 1) * 8 + j];
            tgn[j] = v.x >> 15; ddn[j] = __int_as_float(v.y);
            xsn[j] = cx[(g + 1) * 8 + j];
          }
#pragma unroll
          for (int j = 0; j < 8; j++) {
            int tg_s = __builtin_amdgcn_readfirstlane(tg[j]);
            edge_step_r1(tg_s, dd[j], xs[j], cur_s, p0, p1, s0, s1, s_xt, s_S, cp,
                         wd0, wd1, uP0, uP1, vP0, vP1, uQ0, uQ1, tile0);
          }
#pragma unroll
          for (int j = 0; j < 8; j++) { tg[j] = tgn[j]; dd[j] = ddn[j]; xs[j] = xsn[j]; }
        }
        // commit next chunk, then group 7 (prefetching next-chunk group 0)
        ebuf[ns * 64 + lane] = vnext;
        xsb[ns * 64 + lane] = xnext;
        asm volatile("s_waitcnt lgkmcnt(0)" ::: "memory");
        {
          int tgn[8]; float ddn[8]; float xsn[8];
#pragma unroll
          for (int j = 0; j < 8; j++) {
            int2 v = nb[j];
            tgn[j] = v.x >> 15; ddn[j] = __int_as_float(v.y);
            xsn[j] = nx[j];
          }
#pragma unroll
          for (int j = 0; j < 8; j++) {
            int tg_s = __builtin_amdgcn_readfirstlane(tg[j]);
            edge_step_r1(tg_s, dd[j], xs[j], cur_s, p0, p1, s0, s1, s_xt, s_S, cp,
                         wd0, wd1, uP0, uP1, vP0, vP1, uQ0, uQ1, tile0);
          }
#pragma unroll
          for (int j = 0; j < 8; j++) { tg[j] = tgn[j]; dd[j] = ddn[j]; xs[j] = xsn[j]; }
        }
      }
      if (cur_s >= 0) {
        float* dst = &s_S[(cur_s - tile0) * HN + cp];
        atomicAdd(dst, s0);
        atomicAdd(dst + 1, s1);
      }
    }
  } else {
    if (nchunks > 0) {
      int2* ebuf = (int2*)(s_A + (w * 4) * ASTRIDE);
      {
        int e = wstart + lane;
        int2 v;
        if (e < wend) v = es8[e];
        else { v.x = (int)0xFFFF8000; v.y = 0; }
        ebuf[lane] = v;
      }
      asm volatile("s_waitcnt lgkmcnt(0)" ::: "memory");
      int tg[8]; float dd[8]; unsigned qv[8];
#pragma unroll
      for (int j = 0; j < 8; j++) {
        int2 v = ebuf[j];
        tg[j] = v.x >> 15; dd[j] = __int_as_float(v.y);
        qv[j] = *(const unsigned*)&Q[(size_t)(v.x & 0x7fff) * HN + cp];
      }

      for (int ci = 0; ci < nchunks; ci++) {
        const int2* cb = ebuf + (ci & 1) * 64;
        const int2* nb = ebuf + ((ci + 1) & 1) * 64;
        int2 vnext; vnext.x = (int)0xFFFF8000; vnext.y = 0;
        {
          int e = wstart + (ci + 1) * 64 + lane;
          if (ci + 1 < nchunks && e < wend) vnext = es8[e];
        }
#pragma unroll
        for (int g = 0; g < 7; g++) {
          int tgn[8]; float ddn[8]; unsigned qvn[8];
#pragma unroll
          for (int j = 0; j < 8; j++) {
            int2 v = cb[(g + 1) * 8 + j];
            tgn[j] = v.x >> 15; ddn[j] = __int_as_float(v.y);
            qvn[j] = *(const unsigned*)&Q[(size_t)(v.x & 0x7fff) * HN + cp];
          }
#pragma unroll
          for (int j = 0; j < 8; j++) {
            int tg_s = __builtin_amdgcn_readfirstlane(tg[j]);
            edge_step_lds(tg_s, dd[j], qv[j], cur_s, p0, p1, s0, s1, P, s_S, cp, wd0, wd1, tile0);
          }
#pragma unroll
          for (int j = 0; j < 8; j++) { tg[j] = tgn[j]; dd[j] = ddn[j]; qv[j] = qvn[j]; }
        }
        ebuf[((ci + 1) & 1) * 64 + lane] = vnext;
        asm volatile("s_waitcnt lgkmcnt(0)" ::: "memory");
        {
          int tgn[8]; float ddn[8]; unsigned qvn[8];
#pragma unroll
          for (int j = 0; j < 8; j++) {
            int2 v = nb[j];
            tgn[j] = v.x >> 15; ddn[j] = __int_as_float(v.y);
            qvn[j] = *(const unsigned*)&Q[(size_t)(v.x & 0x7fff) * HN + cp];
          }
#pragma unroll
          for (int j = 0; j < 8; j++) {
            int tg_s = __builtin_amdgcn_readfirstlane(tg[j]);
            edge_step_lds(tg_s, dd[j], qv[j], cur_s, p0, p1, s0, s1, P, s_S, cp, wd0, wd1, tile0);
          }
#pragma unroll
          for (int j = 0; j < 8; j++) { tg[j] = tgn[j]; dd[j] = ddn[j]; qv[j] = qvn[j]; }
        }
      }
      if (cur_s >= 0) {
        float* dst = &s_S[(cur_s - tile0) * HN + cp];
        atomicAdd(dst, s0);
        atomicAdd(dst + 1, s1);
      }
    }
  }
  __syncthreads();  // s_S complete; s_A free for A-tile

  // ================= phase 2: node MLP (8-way: rh x ch) =================
  // stage s_S -> s_A bf16: wave w stages rows w*4..w*4+3
  {
    int srow = w * 4 + (lane >> 4);
    int scol = (lane & 15) * 8;
    const float4* src = (const float4*)&s_S[srow * HN + scol];
    u16* dst = s_A + srow * ASTRIDE + scol;
    float4 v0 = src[0];
    float4 v1 = src[1];
    ushort4 o0, o1;
    o0.x = f2bf(v0.x); o0.y = f2bf(v0.y); o0.z = f2bf(v0.z); o0.w = f2bf(v0.w);
    o1.x = f2bf(v1.x); o1.y = f2bf(v1.y); o1.z = f2bf(v1.z); o1.w = f2bf(v1.w);
    *(ushort4*)(dst + 0) = o0;
    *(ushort4*)(dst + 4) = o1;
  }
  __syncthreads();  // cross-wave A reads

  float bb1[2], vcr[2], bb2[2], bbn[2];
#pragma unroll
  for (int ct = 0; ct < 2; ct++) {
    int c = (ch * 2 + ct) * 16 + m16;
    bb1[ct] = b1[c];
    vcr[ct] = vc[c];
    bb2[ct] = b2[c];
    bbn[ct] = FUSE ? b1_next[c] : 0.f;
  }
  int nodem = tile0 + rh * 16 + m16;
  if (nodem >= nnodes) nodem = nnodes - 1;

  f32x4 acc[2];
#pragma unroll
  for (int ct = 0; ct < 2; ct++) acc[ct] = {0.f, 0.f, 0.f, 0.f};
  gemm32q_gb(s_A, pwc, rh, ch, quad, m16, acc);        // S@Wc (eighth)

  bf16x8 aH[4];
  if constexpr (RANK1) {
    float xv = s_xt[rh * 16 + m16];
#pragma unroll
    for (int ks = 0; ks < 4; ks++) {
      u16 hv[8];
#pragma unroll
      for (int i = 0; i < 8; i++) {
        int c = ks * 32 + quad * 8 + i;
        hv[i] = f2bf(fmaf(xv, emb_w[c], emb_b[c]));
      }
      aH[ks] = *(bf16x8*)hv;
    }
  } else {
#pragma unroll
    for (int ks = 0; ks < 4; ks++)
      aH[ks] = *(const bf16x8*)&hbf[(size_t)nodem * HN + ks * 32 + quad * 8];
  }
  gemm32q_ra_gb(aH, pwn, ch, quad, m16, acc);          // + h@W1a

  // silu(acc + deg*vc + b1) -> own (row-range x col-quarter) of s_A
  {
    float degv[4];
#pragma unroll
    for (int j = 0; j < 4; j++) {
      int n = tile0 + rh * 16 + quad * 4 + j;
      if (n >= nnodes) n = nnodes - 1;
      degv[j] = (float)deg[n];
    }
#pragma unroll
    for (int ct = 0; ct < 2; ct++)
#pragma unroll
      for (int j = 0; j < 4; j++) {
        int row = rh * 16 + quad * 4 + j;
        float xv = acc[ct][j] + bb1[ct] + degv[j] * vcr[ct];
        s_A[row * ASTRIDE + (ch * 2 + ct) * 16 + m16] = f2bf(silu_f(xv));
      }
  }
  __syncthreads();  // full rows needed by all col-quarter waves

#pragma unroll
  for (int ct = 0; ct < 2; ct++) acc[ct] = {0.f, 0.f, 0.f, 0.f};
  gemm32q_gb(s_A, pwn + 32768, rh, ch, quad, m16, acc); // hidden@W2n

  // h' = acc + b2: store hout; FUSE: also into s_A
#pragma unroll
  for (int ct = 0; ct < 2; ct++)
#pragma unroll
    for (int j = 0; j < 4; j++) {
      int row = rh * 16 + quad * 4 + j;
      int n = tile0 + row;
      u16 hv = f2bf(acc[ct][j] + bb2[ct]);
      if (n < nnodes) hout[(size_t)n * HN + (ch * 2 + ct) * 16 + m16] = hv;
      if (FUSE) s_A[row * ASTRIDE + (ch * 2 + ct) * 16 + m16] = hv;
    }

  if (FUSE) {
    __syncthreads();  // full h' rows for all col-quarters
#pragma unroll
    for (int ct = 0; ct < 2; ct++) acc[ct] = {0.f, 0.f, 0.f, 0.f};
    gemm32q_gb(s_A, pw_next, rh, ch, quad, m16, acc);  // h'@msgW1a'
#pragma unroll
    for (int ct = 0; ct < 2; ct++)
#pragma unroll
      for (int j = 0; j < 4; j++) {
        int n = tile0 + rh * 16 + quad * 4 + j;
        if (n < nnodes) Pout[(size_t)n * HN + (ch * 2 + ct) * 16 + m16] = f2bf(acc[ct][j] + bbn[ct]);
      }
#pragma unroll
    for (int ct = 0; ct < 2; ct++) acc[ct] = {0.f, 0.f, 0.f, 0.f};
    gemm32q_gb(s_A, pw_next + 16384, rh, ch, quad, m16, acc);  // h'@msgW1b'
#pragma unroll
    for (int ct = 0; ct < 2; ct++)
#pragma unroll
      for (int j = 0; j < 4; j++) {
        int n = tile0 + rh * 16 + quad * 4 + j;
        if (n < nnodes) Qout[(size_t)n * HN + (ch * 2 + ct) * 16 + m16] = f2bf(acc[ct][j]);
      }
  }
}

// ---- pool: 469 blocks x 256 thr; thread = (colpair, rowgroup of 16) ----
__global__ __launch_bounds__(256) void pool_kernel(
    const u16* __restrict__ h, const int* __restrict__ batch,
    float* __restrict__ g, int N) {
  __shared__ int s_b[64];
  const int t = threadIdx.x;
  const int n0 = blockIdx.x * 64;
  if (t < 64) {
    int n = n0 + t;
    s_b[t] = (n < N) ? batch[n] : -1;
  }
  __syncthreads();
  const int cp = (t & 63) * 2;
  const int rg = t >> 6;
  int cur = -1;
  float s0 = 0.f, s1 = 0.f;
#pragma unroll 4
  for (int i = 0; i < 16; i++) {
    int r = rg * 16 + i;
    int b = s_b[r];
    if (b < 0) break;  // sorted; -1 only at tail
    if (b != cur) {
      if (cur >= 0) {
        atomicAdd(&g[cur * HN + cp], s0);
        atomicAdd(&g[cur * HN + cp + 1], s1);
      }
      cur = b; s0 = 0.f; s1 = 0.f;
    }
    unsigned v = *(const unsigned*)&h[(size_t)(n0 + r) * HN + cp];
    s0 += bf2f((u16)(v & 0xffffu));
    s1 += bf2f((u16)(v >> 16));
  }
  if (cur >= 0) {
    atomicAdd(&g[cur * HN + cp], s0);
    atomicAdd(&g[cur * HN + cp + 1], s1);
  }
}

// ---- out: one block per graph, split-K halves + shuffle reduce ----
__global__ __launch_bounds__(64) void out_kernel(
    const float* __restrict__ g, const float* __restrict__ w1,
    const float* __restrict__ b1, const float* __restrict__ w2,
    const float* __restrict__ b2, float* __restrict__ out) {
  const int gi = blockIdx.x;
  const int t = threadIdx.x;
  const int c = t & 31, kh = t >> 5;
  float s = 0.f;
  for (int k = kh * 64; k < kh * 64 + 64; k++)
    s += g[gi * HN + k] * w1[k * 32 + c];
  s += __shfl_down(s, 32);
  float r = 0.f;
  if (kh == 0) r = silu_f(s + b1[c]) * w2[c];
  r += __shfl_down(r, 16);
  r += __shfl_down(r, 8);
  r += __shfl_down(r, 4);
  r += __shfl_down(r, 2);
  r += __shfl_down(r, 1);
  if (t == 0) out[gi] = r + b2[0];
}

extern "C" void kernel_launch(void* const* d_in, const int* in_sizes, int n_in,
                              void* d_out, int out_size, void* d_ws, size_t ws_size,
                              hipStream_t stream) {
  const float* x = (const float*)d_in[0];
  const float* pos = (const float*)d_in[1];
  const int* eidx = (const int*)d_in[2];
  const int* batch = (const int*)d_in[3];
  const float* emb_w = (const float*)d_in[4];
  const float* emb_b = (const float*)d_in[5];
  const float* msg_w1 = (const float*)d_in[6];
  const float* msg_b1 = (const float*)d_in[7];
  const float* msg_w2 = (const float*)d_in[8];
  const float* msg_b2 = (const float*)d_in[9];
  const float* node_w1 = (const float*)d_in[10];
  const float* node_b1 = (const float*)d_in[11];
  const float* node_w2 = (const float*)d_in[12];
  const float* node_b2 = (const float*)d_in[13];
  const float* out_w1 = (const float*)d_in[14];
  const float* out_b1 = (const float*)d_in[15];
  const float* out_w2 = (const float*)d_in[16];
  const float* out_b2 = (const float*)d_in[17];
  float* outp = (float*)d_out;

  const int N = 30000, E = 600000, G = 64;
  const size_t NH = (size_t)N * HN;

  u16* hA = (u16*)d_ws;                       // N*128 bf16
  u16* hB = hA + NH;                          // N*128 bf16
  u16* Pa = hB + NH;                          // N*128 bf16 (P ping)
  u16* Qa = Pa + NH;                          // N*128 bf16 (Q ping)
  u16* Pb = Qa + NH;                          // N*128 bf16 (P pong)
  u16* Qb = Pb + NH;                          // N*128 bf16 (Q pong)
  int2* es8 = (int2*)(Qb + NH);               // E int2 (src|tgt<<15, dist)
  int* deg = (int*)(es8 + E);                 // N
  int* off = deg + N;                         // N
  int* bsum = off + N;                        // 128
  float* g = (float*)(bsum + 128);            // 64*128 f32
  u16* pw = (u16*)(g + G * HN);               // 4*6*16384 bf16
  u16* pwc = pw + (size_t)4 * 6 * 16384;      // 4*16384 bf16 (folded Wc)
  float* vcb = (float*)(pwc + (size_t)4 * 16384);  // 4*128 f32
  float* uvb = vcb + 4 * 128;                 // 3*128 f32 (layer-0 rank-1 vecs)
  int* rnk = (int*)Pb;                        // E ints, aliases P-pong (dead before layer0)

  const int NB = (N + 255) / 256;
  const int NLB = (N + LTM - 1) / LTM;

  // pack + zero deg/g (replaces memsets)
  pack_weights<<<(4 * 6 * 16384 + 255) / 256, 256, 0, stream>>>(
      msg_w1, msg_w2, node_w1, node_w2, pw, deg, g, N, G * HN);
  fold_kernel<<<8, 256, 0, stream>>>(msg_w2, node_w1, msg_b2, pw, pwc, vcb,
                                     msg_w1, emb_w, emb_b, msg_b1, uvb);

  // counting sort by target (rank precomputed in hist -> atomic-free scatter)
  hist_kernel<<<(E + 255) / 256, 256, 0, stream>>>(eidx, deg, rnk, E);
  scan1_kernel<<<NB, 256, 0, stream>>>(deg, off, bsum, N);
  scan2_kernel<<<1, 256, 0, stream>>>(bsum, NB);
  scan3_kernel<<<NB, 256, 0, stream>>>(off, bsum, N);
  scatter_kernel<<<(E + 255) / 256, 256, 0, stream>>>(eidx, pos, off, rnk, es8, E);

  // NOTE: no proj kernel — layer 0 uses the rank-1 path (h0 = x*emb_w + emb_b)

  for (int l = 0; l < 4; l++) {
    const u16* pwl = pw + (size_t)(l * 6) * 16384;
    const float* w1d = msg_w1 + (size_t)(l * 257 + 256) * 128;
    u16* hin = (l & 1) ? hA : hB;   // l0: unused
    u16* hot = (l & 1) ? hB : hA;   // l0->hA, l1->hB, l2->hA, l3->hB
    u16* Pin = (l & 1) ? Pb : Pa;   // l1 reads Pb (l0 out), l2 reads Pa, l3 reads Pb
    u16* Qin = (l & 1) ? Qb : Qa;
    u16* Pot = (l & 1) ? Pa : Pb;
    u16* Qot = (l & 1) ? Qa : Qb;
    if (l == 0) {
      layer_kernel<true, true><<<NLB, 512, 0, stream>>>(
          Pin, Qin, hin, hot, off, deg, w1d, es8,
          pwc + (size_t)l * 16384, vcb + l * 128,
          pwl + 3 * 16384, node_b1 + l * 128, node_b2 + l * 128,
          pw + (size_t)((l + 1) * 6) * 16384, msg_b1 + (l + 1) * 128, Pot, Qot,
          x, uvb, emb_w, emb_b, N, E);
    } else if (l < 3) {
      layer_kernel<true, false><<<NLB, 512, 0, stream>>>(
          Pin, Qin, hin, hot, off, deg, w1d, es8,
          pwc + (size_t)l * 16384, vcb + l * 128,
          pwl + 3 * 16384, node_b1 + l * 128, node_b2 + l * 128,
          pw + (size_t)((l + 1) * 6) * 16384, msg_b1 + (l + 1) * 128, Pot, Qot,
          x, uvb, emb_w, emb_b, N, E);
    } else {
      layer_kernel<false, false><<<NLB, 512, 0, stream>>>(
          Pin, Qin, hin, hot, off, deg, w1d, es8,
          pwc + (size_t)l * 16384, vcb + l * 128,
          pwl + 3 * 16384, node_b1 + l * 128, node_b2 + l * 128,
          nullptr, nullptr, nullptr, nullptr,
          x, uvb, emb_w, emb_b, N, E);
    }
  }

  pool_kernel<<<(N + 63) / 64, 256, 0, stream>>>(hB, batch, g, N);
  out_kernel<<<G, 64, 0, stream>>>(g, out_w1, out_b1, out_w2, out_b2, outp);
}

// Round 11
// 397.292 us; speedup vs baseline: 1.0025x; 1.0025x over previous
//
#include <hip/hip_runtime.h>

typedef unsigned short u16;
typedef __bf16 bf16x8 __attribute__((ext_vector_type(8)));
typedef float f32x4 __attribute__((ext_vector_type(4)));

#define HN 128
#define TM 64
#define LTM 32        // layer-kernel tile (32 nodes/block, 938 blocks)
#define ASTRIDE 136   // 128 + 8 pad (u16), rows 16B-aligned

__device__ __forceinline__ u16 f2bf(float f) {
  union { float f; unsigned u; } v; v.f = f;
  unsigned r = v.u + 0x7fffu + ((v.u >> 16) & 1u);
  return (u16)(r >> 16);
}
__device__ __forceinline__ float bf2f(u16 v) {
  union { unsigned u; float f; } x; x.u = ((unsigned)v) << 16; return x.f;
}
__device__ __forceinline__ float bflo(unsigned v) {
  union { unsigned u; float f; } x; x.u = v << 16; return x.f;
}
__device__ __forceinline__ float bfhi(unsigned v) {
  union { unsigned u; float f; } x; x.u = v & 0xffff0000u; return x.f;
}
// fast silu: x * rcp(1 + exp2(-log2e*x)) — v_exp_f32/v_rcp_f32, ~1 ulp
__device__ __forceinline__ float silu_f(float x) {
  float e = __builtin_amdgcn_exp2f(-1.442695041f * x);
  return x * __builtin_amdgcn_rcpf(1.f + e);
}

// ---- pack weights into MFMA B-fragment layout: P[kg][n][8], kg=k/8 ----
// mats per layer: 0=msgW1a 1=msgW1b 2=msgW2 3=nodeW1a 4=nodeW1b 5=nodeW2
// Also zeroes deg[N].
__global__ void pack_weights(const float* __restrict__ msg_w1, const float* __restrict__ msg_w2,
                             const float* __restrict__ node_w1, const float* __restrict__ node_w2,
                             u16* __restrict__ pw, int* __restrict__ deg, int N_) {
  int id = blockIdx.x * 256 + threadIdx.x;
  if (id < N_) deg[id] = 0;
  if (id >= 4 * 6 * 16384) return;
  int l = id / (6 * 16384);
  int rem = id % (6 * 16384);
  int m = rem / 16384;
  int e = rem % 16384;
  int kg = e >> 10;
  int n = (e >> 3) & 127;
  int j = e & 7;
  int k = kg * 8 + j;
  float v = 0.f;
  switch (m) {
    case 0: v = msg_w1[(l * 257 + k) * 128 + n]; break;
    case 1: v = msg_w1[(l * 257 + 128 + k) * 128 + n]; break;
    case 2: v = msg_w2[(l * 128 + k) * 128 + n]; break;
    case 3: v = node_w1[(l * 256 + k) * 128 + n]; break;
    case 4: v = node_w1[(l * 256 + 128 + k) * 128 + n]; break;
    case 5: v = node_w2[(l * 128 + k) * 128 + n]; break;
  }
  pw[id] = f2bf(v);
}

// A from LDS band (rows w*16..w*16+15), B from LDS (64-row tile kernels)
__device__ __forceinline__ void gemm64(const u16* s_A, const u16* s_W,
                                       int w, int quad, int m16, f32x4 acc[8]) {
#pragma unroll
  for (int ks = 0; ks < 4; ks++) {
    bf16x8 a = *(const bf16x8*)&s_A[(w * 16 + m16) * ASTRIDE + ks * 32 + quad * 8];
#pragma unroll
    for (int ct = 0; ct < 8; ct++) {
      bf16x8 b = *(const bf16x8*)&s_W[(ks * 4 + quad) * 1024 + (ct * 16 + m16) * 8];
      acc[ct] = __builtin_amdgcn_mfma_f32_16x16x32_bf16(a, b, acc[ct], 0, 0, 0);
    }
  }
}

// quarter-gemm: A rows rh*16.., B col-half ch (ct' = ch*4+ct); B from global (L2)
__device__ __forceinline__ void gemm32_gb(const u16* s_A, const u16* __restrict__ gW,
                                          int rh, int ch, int quad, int m16, f32x4 acc[4]) {
#pragma unroll
  for (int ks = 0; ks < 4; ks++) {
    bf16x8 a = *(const bf16x8*)&s_A[(rh * 16 + m16) * ASTRIDE + ks * 32 + quad * 8];
#pragma unroll
    for (int ct = 0; ct < 4; ct++) {
      bf16x8 b = *(const bf16x8*)&gW[(ks * 4 + quad) * 1024 + ((ch * 4 + ct) * 16 + m16) * 8];
      acc[ct] = __builtin_amdgcn_mfma_f32_16x16x32_bf16(a, b, acc[ct], 0, 0, 0);
    }
  }
}

// quarter-gemm, A from registers
__device__ __forceinline__ void gemm32_ra_gb(const bf16x8 aH[4], const u16* __restrict__ gW,
                                             int ch, int quad, int m16, f32x4 acc[4]) {
#pragma unroll
  for (int ks = 0; ks < 4; ks++) {
#pragma unroll
    for (int ct = 0; ct < 4; ct++) {
      bf16x8 b = *(const bf16x8*)&gW[(ks * 4 + quad) * 1024 + ((ch * 4 + ct) * 16 + m16) * 8];
      acc[ct] = __builtin_amdgcn_mfma_f32_16x16x32_bf16(aH[ks], b, acc[ct], 0, 0, 0);
    }
  }
}

// ---- fold: Wc = msgW2 @ nodeW1b (bf16, B-frag packed), vc = msg_b2 @ nodeW1b.
// Block (l=0,half=1) also computes layer-0 rank-1 vectors:
//   uv = [uP | vP+vQ+b1 | uQ], uP=emb_w@msgW1a etc. ----
__global__ __launch_bounds__(256) void fold_kernel(
    const float* __restrict__ msg_w2, const float* __restrict__ node_w1,
    const float* __restrict__ msg_b2, const u16* __restrict__ pw,
    u16* __restrict__ pwc, float* __restrict__ vc,
    const float* __restrict__ msg_w1, const float* __restrict__ emb_w,
    const float* __restrict__ emb_b, const float* __restrict__ msg_b1,
    float* __restrict__ uv) {
  __shared__ __align__(16) u16 s_A[TM * ASTRIDE];
  __shared__ __align__(16) u16 s_W[16384];
  const int t = threadIdx.x;
  const int w = t >> 6, lane = t & 63, quad = lane >> 4, m16 = lane & 15;
  const int b = blockIdx.x, l = b >> 1, half = b & 1;
  const int tile0 = half * 64;

  {
    int r = t >> 2, qo = (t & 3) * 32;
    const float4* src = (const float4*)(msg_w2 + (size_t)(l * 128 + tile0 + r) * 128 + qo);
    u16* dst = s_A + r * ASTRIDE + qo;
#pragma unroll
    for (int i = 0; i < 8; i++) {
      float4 v = src[i];
      ushort4 o;
      o.x = f2bf(v.x); o.y = f2bf(v.y); o.z = f2bf(v.z); o.w = f2bf(v.w);
      *(ushort4*)(dst + i * 4) = o;
    }
  }
  {
    const int4* src = (const int4*)(pw + (size_t)(l * 6 + 4) * 16384);
    int4* dst = (int4*)s_W;
#pragma unroll
    for (int i = 0; i < 8; i++) dst[t + i * 256] = src[t + i * 256];
  }
  __syncthreads();
  f32x4 acc[8];
#pragma unroll
  for (int ct = 0; ct < 8; ct++) acc[ct] = {0.f, 0.f, 0.f, 0.f};
  gemm64(s_A, s_W, w, quad, m16, acc);
#pragma unroll
  for (int ct = 0; ct < 8; ct++)
#pragma unroll
    for (int j = 0; j < 4; j++) {
      int k = tile0 + w * 16 + quad * 4 + j;
      int n = ct * 16 + m16;
      pwc[(size_t)l * 16384 + (k >> 3) * 1024 + n * 8 + (k & 7)] = f2bf(acc[ct][j]);
    }
  if (half == 0 && t < 128) {
    float s = 0.f;
    for (int np = 0; np < 128; np++)
      s += msg_b2[l * 128 + np] * node_w1[(size_t)(l * 256 + 128 + np) * 128 + t];
    vc[l * 128 + t] = s;
  }
  if (l == 0 && half == 1 && t < 128) {
    float up = 0.f, vp = 0.f, uq = 0.f, vq = 0.f;
    for (int k = 0; k < 128; k++) {
      float wa = msg_w1[(size_t)k * 128 + t];          // l=0 msgW1a rows
      float wb = msg_w1[(size_t)(128 + k) * 128 + t];  // l=0 msgW1b rows
      up = fmaf(emb_w[k], wa, up);
      vp = fmaf(emb_b[k], wa, vp);
      uq = fmaf(emb_w[k], wb, uq);
      vq = fmaf(emb_b[k], wb, vq);
    }
    uv[t] = up;
    uv[128 + t] = vp + vq + msg_b1[t];
    uv[256 + t] = uq;
  }
}

// ---- counting sort of edges by target; rank = arrival order per target. ----
__global__ void hist_kernel(const int* __restrict__ eidx, int* __restrict__ deg,
                            int* __restrict__ rnk, int E_) {
  int e = blockIdx.x * 256 + threadIdx.x;
  if (e < E_) rnk[e] = atomicAdd(&deg[eidx[E_ + e]], 1);
}

__global__ void scan1_kernel(const int* __restrict__ deg, int* __restrict__ off,
                             int* __restrict__ bsum, int n) {
  __shared__ int s[256];
  int t = threadIdx.x;
  int i = blockIdx.x * 256 + t;
  int v = (i < n) ? deg[i] : 0;
  s[t] = v;
  for (int d = 1; d < 256; d <<= 1) {
    __syncthreads();
    int x = (t >= d) ? s[t - d] : 0;
    __syncthreads();
    s[t] += x;
  }
  __syncthreads();
  if (i < n) off[i] = s[t] - v;  // block-local exclusive (bsum added at use sites)
  if (t == 255) bsum[blockIdx.x] = s[255];
}

__global__ void scan2_kernel(int* __restrict__ bsum, int nb) {
  __shared__ int s[256];
  int t = threadIdx.x;
  int v = (t < nb) ? bsum[t] : 0;
  s[t] = v;
  for (int d = 1; d < 256; d <<= 1) {
    __syncthreads();
    int x = (t >= d) ? s[t - d] : 0;
    __syncthreads();
    s[t] += x;
  }
  __syncthreads();
  if (t < nb) bsum[t] = s[t] - v;  // exclusive block offsets
}

// scatter edges into target-sorted order — NO atomics (rank precomputed).
// Global offset = off[tg] (block-local) + bsum[tg>>8] (scanned) — scan3 folded in.
// es8[p] = (src | tgt<<15, dist_bits): 8 B/edge (N < 2^15).
__global__ void scatter_kernel(const int* __restrict__ eidx, const float* __restrict__ pos,
                               const int* __restrict__ off, const int* __restrict__ bsum,
                               const int* __restrict__ rnk, int2* __restrict__ es8, int E_) {
  int e = blockIdx.x * 256 + threadIdx.x;
  if (e >= E_) return;
  int sr = eidx[e], tg = eidx[E_ + e];
  float dx = pos[sr * 3 + 0] - pos[tg * 3 + 0];
  float dy = pos[sr * 3 + 1] - pos[tg * 3 + 1];
  float dz = pos[sr * 3 + 2] - pos[tg * 3 + 2];
  float d = dx * dx + dy * dy + dz * dz;
  int p = off[tg] + bsum[tg >> 8] + rnk[e];
  int2 v;
  v.x = sr | (tg << 15);
  v.y = __float_as_int(d);
  es8[p] = v;
}

// edge step with LDS-accumulator close (all targets are block-local).
// PAD GUARD: tg_s is an SGPR; pads (tg_s<0) skip the VALU body entirely.
__device__ __forceinline__ void edge_step_lds(
    int tg_s, float dd_s, unsigned qv,
    int& cur_s, float& p0, float& p1, float& s0, float& s1,
    const u16* __restrict__ P, float* s_S, int cp,
    float wd0, float wd1, int tile0) {
  if (tg_s < 0) return;  // scalar branch: pad slot
  if (tg_s != cur_s) {   // wave-uniform branch
    if (cur_s >= 0) {
      float* dst = &s_S[(cur_s - tile0) * HN + cp];
      atomicAdd(dst, s0);
      atomicAdd(dst + 1, s1);
    }
    cur_s = tg_s; s0 = 0.f; s1 = 0.f;
    unsigned pv = *(const unsigned*)&P[(size_t)tg_s * HN + cp];
    p0 = bflo(pv); p1 = bfhi(pv);
  }
  float x0 = p0 + bflo(qv) + dd_s * wd0;
  float x1 = p1 + bfhi(qv) + dd_s * wd1;
  s0 += silu_f(x0);
  s1 += silu_f(x1);
}

// rank-1 edge step (layer 0): P/Q replaced by affine functions of x
__device__ __forceinline__ void edge_step_r1(
    int tg_s, float dd_s, float xs,
    int& cur_s, float& p0, float& p1, float& s0, float& s1,
    const float* s_xt, float* s_S, int cp,
    float wd0, float wd1, float uP0, float uP1, float vP0, float vP1,
    float uQ0, float uQ1, int tile0) {
  if (tg_s < 0) return;  // scalar branch: pad slot
  if (tg_s != cur_s) {   // wave-uniform branch
    if (cur_s >= 0) {
      float* dst = &s_S[(cur_s - tile0) * HN + cp];
      atomicAdd(dst, s0);
      atomicAdd(dst + 1, s1);
    }
    cur_s = tg_s; s0 = 0.f; s1 = 0.f;
    float xt = s_xt[tg_s - tile0];
    p0 = fmaf(xt, uP0, vP0);
    p1 = fmaf(xt, uP1, vP1);
  }
  float x0 = fmaf(dd_s, wd0, fmaf(xs, uQ0, p0));
  float x1 = fmaf(dd_s, wd1, fmaf(xs, uQ1, p1));
  s0 += silu_f(x0);
  s1 += silu_f(x1);
}

// ---- FUSED layer kernel, LTM=32 (938 blocks) — R7 structure (best measured).
// RANK1 (layer 0): P/Q/h are affine in x — no gathers, no proj kernel.
// Phase 1: wave-autonomous edge ranges into s_S (LDS accumulate), LDS-staged
//   double-buffered es8 pipeline, 8-deep Q prefetch; pads skipped via scalar
//   guard. Phase 2: 32x128 MLP in (row-half x col-half) quarters. ----
template <bool FUSE, bool RANK1>
__global__ __launch_bounds__(256) void layer_kernel(
    const u16* __restrict__ P, const u16* __restrict__ Q,
    const u16* __restrict__ hbf, u16* __restrict__ hout,
    const int* __restrict__ off, const int* __restrict__ bsum,
    const int* __restrict__ deg,
    const float* __restrict__ w1d, const int2* __restrict__ es8,
    const u16* __restrict__ pwc, const float* __restrict__ vc,
    const u16* __restrict__ pwn, const float* __restrict__ b1, const float* __restrict__ b2,
    const u16* __restrict__ pw_next, const float* __restrict__ b1_next,
    u16* __restrict__ Pout, u16* __restrict__ Qout,
    const float* __restrict__ xin, const float* __restrict__ uv,
    const float* __restrict__ emb_w, const float* __restrict__ emb_b,
    int nnodes, int E_) {
  __shared__ float s_S[LTM * HN];                   // 16 KB message accumulators
  __shared__ __align__(16) u16 s_A[LTM * ASTRIDE];  // 8.5 KB: ebuf then A-tile
  __shared__ float s_xt[LTM];                       // x of tile nodes (RANK1)
  const int t = threadIdx.x;
  const int w = t >> 6, lane = t & 63, quad = lane >> 4, m16 = lane & 15;
  const int tile0 = blockIdx.x * LTM;
  const int rh = w >> 1;   // row-half (rows rh*16..rh*16+15)
  const int ch = w & 1;    // col-half (cols ch*64..ch*64+63)

  // zero s_S (16KB = 1024 float4); stage x-tile if RANK1
  {
    float4 z = {0.f, 0.f, 0.f, 0.f};
    float4* p4 = (float4*)s_S;
#pragma unroll
    for (int i = 0; i < 4; i++) p4[t + i * 256] = z;
  }
  if constexpr (RANK1) {
    if (t < LTM) {
      int n = tile0 + t;
      s_xt[t] = (n < nnodes) ? xin[n] : 0.f;
    }
  }
  __syncthreads();

  // ================= phase 1: edges =================
  const int cp = lane * 2;
  const float2 wdv = *(const float2*)&w1d[cp];
  const float wd0 = wdv.x, wd1 = wdv.y;
  const int e_lo = off[tile0] + bsum[tile0 >> 8];
  const int e_hi = (tile0 + LTM < nnodes)
                       ? off[tile0 + LTM] + bsum[(tile0 + LTM) >> 8] : E_;
  const int span = e_hi - e_lo;
  const int wstart = e_lo + (span * w) / 4;
  const int wend = e_lo + (span * (w + 1)) / 4;
  const int total = wend - wstart;
  const int nchunks = (total + 63) >> 6;

  int cur_s = -1;
  float s0 = 0.f, s1 = 0.f, p0 = 0.f, p1 = 0.f;

  if constexpr (RANK1) {
    __shared__ float s_xs[4][2][64];
    const float uP0 = uv[cp], uP1 = uv[cp + 1];
    const float vP0 = uv[128 + cp], vP1 = uv[128 + cp + 1];
    const float uQ0 = uv[256 + cp], uQ1 = uv[256 + cp + 1];
    if (nchunks > 0) {
      int2* ebuf = (int2*)(s_A + (w * 8) * ASTRIDE);
      float* xsb = &s_xs[w][0][0];
      // prologue: chunk 0 (es8 + x[src])
      {
        int e = wstart + lane;
        int2 v;
        if (e < wend) v = es8[e];
        else { v.x = (int)0xFFFF8000; v.y = 0; }
        float xl = xin[v.x & 0x7fff];
        ebuf[lane] = v;
        xsb[lane] = xl;
      }
      asm volatile("s_waitcnt lgkmcnt(0)" ::: "memory");
      int tg[8]; float dd[8]; float xs[8];
#pragma unroll
      for (int j = 0; j < 8; j++) {
        int2 v = ebuf[j];
        tg[j] = v.x >> 15; dd[j] = __int_as_float(v.y);
        xs[j] = xsb[j];
      }

      for (int ci = 0; ci < nchunks; ci++) {
        const int cs = (ci & 1), ns = ((ci + 1) & 1);
        const int2* cb = ebuf + cs * 64;
        const float* cx = xsb + cs * 64;
        const int2* nb = ebuf + ns * 64;
        const float* nx = xsb + ns * 64;
        int2 vnext; vnext.x = (int)0xFFFF8000; vnext.y = 0;
        {
          int e = wstart + (ci + 1) * 64 + lane;
          if (ci + 1 < nchunks && e < wend) vnext = es8[e];
        }
        // groups 0..2 (prefetch g+1 from LDS)
#pragma unroll
        for (int g = 0; g < 3; g++) {
          int tgn[8]; float ddn[8]; float xsn[8];
#pragma unroll
          for (int j = 0; j < 8; j++) {
            int2 v = cb[(g + 1) * 8 + j];
            tgn[j] = v.x >> 15; ddn[j] = __int_as_float(v.y);
            xsn[j] = cx[(g + 1) * 8 + j];
          }
#pragma unroll
          for (int j = 0; j < 8; j++) {
            int tg_s = __builtin_amdgcn_readfirstlane(tg[j]);
            edge_step_r1(tg_s, dd[j], xs[j], cur_s, p0, p1, s0, s1, s_xt, s_S, cp,
                         wd0, wd1, uP0, uP1, vP0, vP1, uQ0, uQ1, tile0);
          }
#pragma unroll
          for (int j = 0; j < 8; j++) { tg[j] = tgn[j]; dd[j] = ddn[j]; xs[j] = xsn[j]; }
        }
        // es8 arrived by now; issue the dependent x gather
        float xnext = xin[vnext.x & 0x7fff];
        // groups 3..6
#pragma unroll
        for (int g = 3; g < 7; g++) {
          int tgn[8]; float ddn[8]; float xsn[8];
#pragma unroll
          for (int j = 0; j < 8; j++) {
            int2 v = cb[(g + 1) * 8 + j];
            tgn[j] = v.x >> 15; ddn[j] = __int_as_float(v.y);
            xsn[j] = cx[(g + 1) * 8 + j];
          }
#pragma unroll
          for (int j = 0; j < 8; j++) {
            int tg_s = __builtin_amdgcn_readfirstlane(tg[j]);
            edge_step_r1(tg_s, dd[j], xs[j], cur_s, p0, p1, s0, s1, s_xt, s_S, cp,
                         wd0, wd1, uP0, uP1, vP0, vP1, uQ0, uQ1, tile0);
          }
#pragma unroll
          for (int j = 0; j < 8; j++) { tg[j] = tgn[j]; dd[j] = ddn[j]; xs[j] = xsn[j]; }
        }
        // commit next chunk, then group 7 (prefetching next-chunk group 0)
        ebuf[ns * 64 + lane] = vnext;
        xsb[ns * 64 + lane] = xnext;
        asm volatile("s_waitcnt lgkmcnt(0)" ::: "memory");
        {
          int tgn[8]; float ddn[8]; float xsn[8];
#pragma unroll
          for (int j = 0; j < 8; j++) {
            int2 v = nb[j];
            tgn[j] = v.x >> 15; ddn[j] = __int_as_float(v.y);
            xsn[j] = nx[j];
          }
#pragma unroll
          for (int j = 0; j < 8; j++) {
            int tg_s = __builtin_amdgcn_readfirstlane(tg[j]);
            edge_step_r1(tg_s, dd[j], xs[j], cur_s, p0, p1, s0, s1, s_xt, s_S, cp,
                         wd0, wd1, uP0, uP1, vP0, vP1, uQ0, uQ1, tile0);
          }
#pragma unroll
          for (int j = 0; j < 8; j++) { tg[j] = tgn[j]; dd[j] = ddn[j]; xs[j] = xsn[j]; }
        }
      }
      if (cur_s >= 0) {
        float* dst = &s_S[(cur_s - tile0) * HN + cp];
        atomicAdd(dst, s0);
        atomicAdd(dst + 1, s1);
      }
    }
  } else {
    if (nchunks > 0) {
      int2* ebuf = (int2*)(s_A + (w * 8) * ASTRIDE);
      {
        int e = wstart + lane;
        int2 v;
        if (e < wend) v = es8[e];
        else { v.x = (int)0xFFFF8000; v.y = 0; }
        ebuf[lane] = v;
      }
      asm volatile("s_waitcnt lgkmcnt(0)" ::: "memory");
      int tg[8]; float dd[8]; unsigned qv[8];
#pragma unroll
      for (int j = 0; j < 8; j++) {
        int2 v = ebuf[j];
        tg[j] = v.x >> 15; dd[j] = __int_as_float(v.y);
        qv[j] = *(const unsigned*)&Q[(size_t)(v.x & 0x7fff) * HN + cp];
      }

      for (int ci = 0; ci < nchunks; ci++) {
        const int2* cb = ebuf + (ci & 1) * 64;
        const int2* nb = ebuf + ((ci + 1) & 1) * 64;
        int2 vnext; vnext.x = (int)0xFFFF8000; vnext.y = 0;
        {
          int e = wstart + (ci + 1) * 64 + lane;
          if (ci + 1 < nchunks && e < wend) vnext = es8[e];
        }
#pragma unroll
        for (int g = 0; g < 7; g++) {
          int tgn[8]; float ddn[8]; unsigned qvn[8];
#pragma unroll
          for (int j = 0; j < 8; j++) {
            int2 v = cb[(g + 1) * 8 + j];
            tgn[j] = v.x >> 15; ddn[j] = __int_as_float(v.y);
            qvn[j] = *(const unsigned*)&Q[(size_t)(v.x & 0x7fff) * HN + cp];
          }
#pragma unroll
          for (int j = 0; j < 8; j++) {
            int tg_s = __builtin_amdgcn_readfirstlane(tg[j]);
            edge_step_lds(tg_s, dd[j], qv[j], cur_s, p0, p1, s0, s1, P, s_S, cp, wd0, wd1, tile0);
          }
#pragma unroll
          for (int j = 0; j < 8; j++) { tg[j] = tgn[j]; dd[j] = ddn[j]; qv[j] = qvn[j]; }
        }
        ebuf[((ci + 1) & 1) * 64 + lane] = vnext;
        asm volatile("s_waitcnt lgkmcnt(0)" ::: "memory");
        {
          int tgn[8]; float ddn[8]; unsigned qvn[8];
#pragma unroll
          for (int j = 0; j < 8; j++) {
            int2 v = nb[j];
            tgn[j] = v.x >> 15; ddn[j] = __int_as_float(v.y);
            qvn[j] = *(const unsigned*)&Q[(size_t)(v.x & 0x7fff) * HN + cp];
          }
#pragma unroll
          for (int j = 0; j < 8; j++) {
            int tg_s = __builtin_amdgcn_readfirstlane(tg[j]);
            edge_step_lds(tg_s, dd[j], qv[j], cur_s, p0, p1, s0, s1, P, s_S, cp, wd0, wd1, tile0);
          }
#pragma unroll
          for (int j = 0; j < 8; j++) { tg[j] = tgn[j]; dd[j] = ddn[j]; qv[j] = qvn[j]; }
        }
      }
      if (cur_s >= 0) {
        float* dst = &s_S[(cur_s - tile0) * HN + cp];
        atomicAdd(dst, s0);
        atomicAdd(dst + 1, s1);
      }
    }
  }
  __syncthreads();  // s_S complete; s_A free for A-tile

  // ================= phase 2: node MLP (quarter-split) =================
  // stage s_S -> s_A bf16: each wave stages 8 rows (rows w*8..w*8+7)
  {
    int srow = w * 8 + (lane >> 3);
    int scol = (lane & 7) * 16;
    const float4* src = (const float4*)&s_S[srow * HN + scol];
    u16* dst = s_A + srow * ASTRIDE + scol;
#pragma unroll
    for (int i = 0; i < 4; i++) {
      float4 v = src[i];
      ushort4 o;
      o.x = f2bf(v.x); o.y = f2bf(v.y); o.z = f2bf(v.z); o.w = f2bf(v.w);
      *(ushort4*)(dst + i * 4) = o;
    }
  }
  __syncthreads();  // cross-wave A reads

  float bb1[4], vcr[4], bb2[4], bbn[4];
#pragma unroll
  for (int ct = 0; ct < 4; ct++) {
    int c = (ch * 4 + ct) * 16 + m16;
    bb1[ct] = b1[c];
    vcr[ct] = vc[c];
    bb2[ct] = b2[c];
    bbn[ct] = FUSE ? b1_next[c] : 0.f;
  }
  int nodem = tile0 + rh * 16 + m16;
  if (nodem >= nnodes) nodem = nnodes - 1;

  f32x4 acc[4];
#pragma unroll
  for (int ct = 0; ct < 4; ct++) acc[ct] = {0.f, 0.f, 0.f, 0.f};
  gemm32_gb(s_A, pwc, rh, ch, quad, m16, acc);         // S@Wc (quarter)

  bf16x8 aH[4];
  if constexpr (RANK1) {
    float xv = s_xt[rh * 16 + m16];
#pragma unroll
    for (int ks = 0; ks < 4; ks++) {
      u16 hv[8];
#pragma unroll
      for (int i = 0; i < 8; i++) {
        int c = ks * 32 + quad * 8 + i;
        hv[i] = f2bf(fmaf(xv, emb_w[c], emb_b[c]));
      }
      aH[ks] = *(bf16x8*)hv;
    }
  } else {
#pragma unroll
    for (int ks = 0; ks < 4; ks++)
      aH[ks] = *(const bf16x8*)&hbf[(size_t)nodem * HN + ks * 32 + quad * 8];
  }
  gemm32_ra_gb(aH, pwn, ch, quad, m16, acc);           // + h@W1a

  // silu(acc + deg*vc + b1) -> own quarter of s_A
  {
    float degv[4];
#pragma unroll
    for (int j = 0; j < 4; j++) {
      int n = tile0 + rh * 16 + quad * 4 + j;
      if (n >= nnodes) n = nnodes - 1;
      degv[j] = (float)deg[n];
    }
#pragma unroll
    for (int ct = 0; ct < 4; ct++)
#pragma unroll
      for (int j = 0; j < 4; j++) {
        int row = rh * 16 + quad * 4 + j;
        float xv = acc[ct][j] + bb1[ct] + degv[j] * vcr[ct];
        s_A[row * ASTRIDE + (ch * 4 + ct) * 16 + m16] = f2bf(silu_f(xv));
      }
  }
  __syncthreads();  // full rows needed by both col-half waves

#pragma unroll
  for (int ct = 0; ct < 4; ct++) acc[ct] = {0.f, 0.f, 0.f, 0.f};
  gemm32_gb(s_A, pwn + 32768, rh, ch, quad, m16, acc); // hidden@W2n

  // h' = acc + b2: store hout quarter; FUSE: also into s_A quarter
#pragma unroll
  for (int ct = 0; ct < 4; ct++)
#pragma unroll
    for (int j = 0; j < 4; j++) {
      int row = rh * 16 + quad * 4 + j;
      int n = tile0 + row;
      u16 hv = f2bf(acc[ct][j] + bb2[ct]);
      if (n < nnodes) hout[(size_t)n * HN + (ch * 4 + ct) * 16 + m16] = hv;
      if (FUSE) s_A[row * ASTRIDE + (ch * 4 + ct) * 16 + m16] = hv;
    }

  if (FUSE) {
    __syncthreads();  // full h' rows for both col-halves
#pragma unroll
    for (int ct = 0; ct < 4; ct++) acc[ct] = {0.f, 0.f, 0.f, 0.f};
    gemm32_gb(s_A, pw_next, rh, ch, quad, m16, acc);   // h'@msgW1a'
#pragma unroll
    for (int ct = 0; ct < 4; ct++)
#pragma unroll
      for (int j = 0; j < 4; j++) {
        int n = tile0 + rh * 16 + quad * 4 + j;
        if (n < nnodes) Pout[(size_t)n * HN + (ch * 4 + ct) * 16 + m16] = f2bf(acc[ct][j] + bbn[ct]);
      }
#pragma unroll
    for (int ct = 0; ct < 4; ct++) acc[ct] = {0.f, 0.f, 0.f, 0.f};
    gemm32_gb(s_A, pw_next + 16384, rh, ch, quad, m16, acc);  // h'@msgW1b'
#pragma unroll
    for (int ct = 0; ct < 4; ct++)
#pragma unroll
      for (int j = 0; j < 4; j++) {
        int n = tile0 + rh * 16 + quad * 4 + j;
        if (n < nnodes) Qout[(size_t)n * HN + (ch * 4 + ct) * 16 + m16] = f2bf(acc[ct][j]);
      }
  }
}

// ---- fused pool+out: one block per graph (batch sorted -> contiguous range
// via binary search). LDS accumulation replaces global atomics; wave 0 runs
// the output MLP. ----
__global__ __launch_bounds__(256) void poolout_kernel(
    const u16* __restrict__ h, const int* __restrict__ batch,
    const float* __restrict__ w1, const float* __restrict__ b1,
    const float* __restrict__ w2, const float* __restrict__ b2,
    float* __restrict__ out, int N) {
  __shared__ float sg[128];
  const int gi = blockIdx.x;
  const int t = threadIdx.x;
  // [start,end) = rows of graph gi
  int lo = 0, hi = N;
  while (lo < hi) { int mid = (lo + hi) >> 1; if (batch[mid] < gi) lo = mid + 1; else hi = mid; }
  const int start = lo;
  hi = N;
  while (lo < hi) { int mid = (lo + hi) >> 1; if (batch[mid] < gi + 1) lo = mid + 1; else hi = mid; }
  const int end = lo;

  const int cp = (t & 63) * 2;  // colpair
  const int rg = t >> 6;        // rowgroup (stride 4)
  if (rg == 0) { sg[cp] = 0.f; sg[cp + 1] = 0.f; }
  __syncthreads();
  float s0 = 0.f, s1 = 0.f;
  for (int r = start + rg; r < end; r += 4) {
    unsigned v = *(const unsigned*)&h[(size_t)r * HN + cp];
    s0 += bf2f((u16)(v & 0xffffu));
    s1 += bf2f((u16)(v >> 16));
  }
  atomicAdd(&sg[cp], s0);
  atomicAdd(&sg[cp + 1], s1);
  __syncthreads();

  if (t < 64) {
    const int c = t & 31, kh = t >> 5;
    float s = 0.f;
    for (int k = kh * 64; k < kh * 64 + 64; k++)
      s += sg[k] * w1[k * 32 + c];
    s += __shfl_down(s, 32);
    float r = 0.f;
    if (kh == 0) r = silu_f(s + b1[c]) * w2[c];
    r += __shfl_down(r, 16);
    r += __shfl_down(r, 8);
    r += __shfl_down(r, 4);
    r += __shfl_down(r, 2);
    r += __shfl_down(r, 1);
    if (t == 0) out[gi] = r + b2[0];
  }
}

extern "C" void kernel_launch(void* const* d_in, const int* in_sizes, int n_in,
                              void* d_out, int out_size, void* d_ws, size_t ws_size,
                              hipStream_t stream) {
  const float* x = (const float*)d_in[0];
  const float* pos = (const float*)d_in[1];
  const int* eidx = (const int*)d_in[2];
  const int* batch = (const int*)d_in[3];
  const float* emb_w = (const float*)d_in[4];
  const float* emb_b = (const float*)d_in[5];
  const float* msg_w1 = (const float*)d_in[6];
  const float* msg_b1 = (const float*)d_in[7];
  const float* msg_w2 = (const float*)d_in[8];
  const float* msg_b2 = (const float*)d_in[9];
  const float* node_w1 = (const float*)d_in[10];
  const float* node_b1 = (const float*)d_in[11];
  const float* node_w2 = (const float*)d_in[12];
  const float* node_b2 = (const float*)d_in[13];
  const float* out_w1 = (const float*)d_in[14];
  const float* out_b1 = (const float*)d_in[15];
  const float* out_w2 = (const float*)d_in[16];
  const float* out_b2 = (const float*)d_in[17];
  float* outp = (float*)d_out;

  const int N = 30000, E = 600000, G = 64;
  const size_t NH = (size_t)N * HN;

  u16* hA = (u16*)d_ws;                       // N*128 bf16
  u16* hB = hA + NH;                          // N*128 bf16
  u16* Pa = hB + NH;                          // N*128 bf16 (P ping)
  u16* Qa = Pa + NH;                          // N*128 bf16 (Q ping)
  u16* Pb = Qa + NH;                          // N*128 bf16 (P pong)
  u16* Qb = Pb + NH;                          // N*128 bf16 (Q pong)
  int2* es8 = (int2*)(Qb + NH);               // E int2 (src|tgt<<15, dist)
  int* deg = (int*)(es8 + E);                 // N
  int* off = deg + N;                         // N (block-local exclusive)
  int* bsum = off + N;                        // 128 (scanned block sums)
  u16* pw = (u16*)(bsum + 128);               // 4*6*16384 bf16
  u16* pwc = pw + (size_t)4 * 6 * 16384;      // 4*16384 bf16 (folded Wc)
  float* vcb = (float*)(pwc + (size_t)4 * 16384);  // 4*128 f32
  float* uvb = vcb + 4 * 128;                 // 3*128 f32 (layer-0 rank-1 vecs)
  int* rnk = (int*)Pb;                        // E ints, aliases P-pong (dead before layer0)

  const int NB = (N + 255) / 256;
  const int NLB = (N + LTM - 1) / LTM;

  // pack + zero deg (replaces memset)
  pack_weights<<<(4 * 6 * 16384 + 255) / 256, 256, 0, stream>>>(
      msg_w1, msg_w2, node_w1, node_w2, pw, deg, N);
  fold_kernel<<<8, 256, 0, stream>>>(msg_w2, node_w1, msg_b2, pw, pwc, vcb,
                                     msg_w1, emb_w, emb_b, msg_b1, uvb);

  // counting sort by target (rank precomputed in hist -> atomic-free scatter;
  // scan3 folded into scatter/layer via off+bsum addressing)
  hist_kernel<<<(E + 255) / 256, 256, 0, stream>>>(eidx, deg, rnk, E);
  scan1_kernel<<<NB, 256, 0, stream>>>(deg, off, bsum, N);
  scan2_kernel<<<1, 256, 0, stream>>>(bsum, NB);
  scatter_kernel<<<(E + 255) / 256, 256, 0, stream>>>(eidx, pos, off, bsum, rnk, es8, E);

  // NOTE: no proj kernel — layer 0 uses the rank-1 path (h0 = x*emb_w + emb_b)

  for (int l = 0; l < 4; l++) {
    const u16* pwl = pw + (size_t)(l * 6) * 16384;
    const float* w1d = msg_w1 + (size_t)(l * 257 + 256) * 128;
    u16* hin = (l & 1) ? hA : hB;   // l0: unused
    u16* hot = (l & 1) ? hB : hA;   // l0->hA, l1->hB, l2->hA, l3->hB
    u16* Pin = (l & 1) ? Pb : Pa;   // l1 reads Pb (l0 out), l2 reads Pa, l3 reads Pb
    u16* Qin = (l & 1) ? Qb : Qa;
    u16* Pot = (l & 1) ? Pa : Pb;
    u16* Qot = (l & 1) ? Qa : Qb;
    if (l == 0) {
      layer_kernel<true, true><<<NLB, 256, 0, stream>>>(
          Pin, Qin, hin, hot, off, bsum, deg, w1d, es8,
          pwc + (size_t)l * 16384, vcb + l * 128,
          pwl + 3 * 16384, node_b1 + l * 128, node_b2 + l * 128,
          pw + (size_t)((l + 1) * 6) * 16384, msg_b1 + (l + 1) * 128, Pot, Qot,
          x, uvb, emb_w, emb_b, N, E);
    } else if (l < 3) {
      layer_kernel<true, false><<<NLB, 256, 0, stream>>>(
          Pin, Qin, hin, hot, off, bsum, deg, w1d, es8,
          pwc + (size_t)l * 16384, vcb + l * 128,
          pwl + 3 * 16384, node_b1 + l * 128, node_b2 + l * 128,
          pw + (size_t)((l + 1) * 6) * 16384, msg_b1 + (l + 1) * 128, Pot, Qot,
          x, uvb, emb_w, emb_b, N, E);
    } else {
      layer_kernel<false, false><<<NLB, 256, 0, stream>>>(
          Pin, Qin, hin, hot, off, bsum, deg, w1d, es8,
          pwc + (size_t)l * 16384, vcb + l * 128,
          pwl + 3 * 16384, node_b1 + l * 128, node_b2 + l * 128,
          nullptr, nullptr, nullptr, nullptr,
          x, uvb, emb_w, emb_b, N, E);
    }
  }

  poolout_kernel<<<G, 256, 0, stream>>>(hB, batch, out_w1, out_b1, out_w2, out_b2,
                                        outp, N);
}

// Round 12
// 391.838 us; speedup vs baseline: 1.0165x; 1.0139x over previous
//
#include <hip/hip_runtime.h>

typedef unsigned short u16;
typedef __bf16 bf16x8 __attribute__((ext_vector_type(8)));
typedef float f32x4 __attribute__((ext_vector_type(4)));

#define HN 128
#define TM 64
#define LTM 32        // layer-kernel tile (32 nodes/block, 938 blocks)
#define ASTRIDE 136   // 128 + 8 pad (u16), rows 16B-aligned

__device__ __forceinline__ u16 f2bf(float f) {
  union { float f; unsigned u; } v; v.f = f;
  unsigned r = v.u + 0x7fffu + ((v.u >> 16) & 1u);
  return (u16)(r >> 16);
}
__device__ __forceinline__ float bf2f(u16 v) {
  union { unsigned u; float f; } x; x.u = ((unsigned)v) << 16; return x.f;
}
__device__ __forceinline__ float bflo(unsigned v) {
  union { unsigned u; float f; } x; x.u = v << 16; return x.f;
}
__device__ __forceinline__ float bfhi(unsigned v) {
  union { unsigned u; float f; } x; x.u = v & 0xffff0000u; return x.f;
}
// fast silu: x * rcp(1 + exp2(-log2e*x)) — v_exp_f32/v_rcp_f32, ~1 ulp
__device__ __forceinline__ float silu_f(float x) {
  float e = __builtin_amdgcn_exp2f(-1.442695041f * x);
  return x * __builtin_amdgcn_rcpf(1.f + e);
}

// ---- pack weights into MFMA B-fragment layout: P[kg][n][8], kg=k/8 ----
// mats per layer: 0=msgW1a 1=msgW1b 2=msgW2 3=nodeW1a 4=nodeW1b 5=nodeW2
// Also zeroes deg[N].
__global__ void pack_weights(const float* __restrict__ msg_w1, const float* __restrict__ msg_w2,
                             const float* __restrict__ node_w1, const float* __restrict__ node_w2,
                             u16* __restrict__ pw, int* __restrict__ deg, int N_) {
  int id = blockIdx.x * 256 + threadIdx.x;
  if (id < N_) deg[id] = 0;
  if (id >= 4 * 6 * 16384) return;
  int l = id / (6 * 16384);
  int rem = id % (6 * 16384);
  int m = rem / 16384;
  int e = rem % 16384;
  int kg = e >> 10;
  int n = (e >> 3) & 127;
  int j = e & 7;
  int k = kg * 8 + j;
  float v = 0.f;
  switch (m) {
    case 0: v = msg_w1[(l * 257 + k) * 128 + n]; break;
    case 1: v = msg_w1[(l * 257 + 128 + k) * 128 + n]; break;
    case 2: v = msg_w2[(l * 128 + k) * 128 + n]; break;
    case 3: v = node_w1[(l * 256 + k) * 128 + n]; break;
    case 4: v = node_w1[(l * 256 + 128 + k) * 128 + n]; break;
    case 5: v = node_w2[(l * 128 + k) * 128 + n]; break;
  }
  pw[id] = f2bf(v);
}

// A from LDS band (rows w*16..w*16+15), B from LDS (64-row tile kernels)
__device__ __forceinline__ void gemm64(const u16* s_A, const u16* s_W,
                                       int w, int quad, int m16, f32x4 acc[8]) {
#pragma unroll
  for (int ks = 0; ks < 4; ks++) {
    bf16x8 a = *(const bf16x8*)&s_A[(w * 16 + m16) * ASTRIDE + ks * 32 + quad * 8];
#pragma unroll
    for (int ct = 0; ct < 8; ct++) {
      bf16x8 b = *(const bf16x8*)&s_W[(ks * 4 + quad) * 1024 + (ct * 16 + m16) * 8];
      acc[ct] = __builtin_amdgcn_mfma_f32_16x16x32_bf16(a, b, acc[ct], 0, 0, 0);
    }
  }
}

// quarter-gemm: A rows rh*16.., B col-half ch (ct' = ch*4+ct); B from global (L2)
__device__ __forceinline__ void gemm32_gb(const u16* s_A, const u16* __restrict__ gW,
                                          int rh, int ch, int quad, int m16, f32x4 acc[4]) {
#pragma unroll
  for (int ks = 0; ks < 4; ks++) {
    bf16x8 a = *(const bf16x8*)&s_A[(rh * 16 + m16) * ASTRIDE + ks * 32 + quad * 8];
#pragma unroll
    for (int ct = 0; ct < 4; ct++) {
      bf16x8 b = *(const bf16x8*)&gW[(ks * 4 + quad) * 1024 + ((ch * 4 + ct) * 16 + m16) * 8];
      acc[ct] = __builtin_amdgcn_mfma_f32_16x16x32_bf16(a, b, acc[ct], 0, 0, 0);
    }
  }
}

// quarter-gemm, A from registers
__device__ __forceinline__ void gemm32_ra_gb(const bf16x8 aH[4], const u16* __restrict__ gW,
                                             int ch, int quad, int m16, f32x4 acc[4]) {
#pragma unroll
  for (int ks = 0; ks < 4; ks++) {
#pragma unroll
    for (int ct = 0; ct < 4; ct++) {
      bf16x8 b = *(const bf16x8*)&gW[(ks * 4 + quad) * 1024 + ((ch * 4 + ct) * 16 + m16) * 8];
      acc[ct] = __builtin_amdgcn_mfma_f32_16x16x32_bf16(aH[ks], b, acc[ct], 0, 0, 0);
    }
  }
}

// ---- fold: Wc = msgW2 @ nodeW1b (bf16, B-frag packed), vc = msg_b2 @ nodeW1b.
// Block (l=0,half=1) also computes layer-0 rank-1 vectors:
//   uv = [uP | vP+vQ+b1 | uQ], uP=emb_w@msgW1a etc. ----
__global__ __launch_bounds__(256) void fold_kernel(
    const float* __restrict__ msg_w2, const float* __restrict__ node_w1,
    const float* __restrict__ msg_b2, const u16* __restrict__ pw,
    u16* __restrict__ pwc, float* __restrict__ vc,
    const float* __restrict__ msg_w1, const float* __restrict__ emb_w,
    const float* __restrict__ emb_b, const float* __restrict__ msg_b1,
    float* __restrict__ uv) {
  __shared__ __align__(16) u16 s_A[TM * ASTRIDE];
  __shared__ __align__(16) u16 s_W[16384];
  const int t = threadIdx.x;
  const int w = t >> 6, lane = t & 63, quad = lane >> 4, m16 = lane & 15;
  const int b = blockIdx.x, l = b >> 1, half = b & 1;
  const int tile0 = half * 64;

  {
    int r = t >> 2, qo = (t & 3) * 32;
    const float4* src = (const float4*)(msg_w2 + (size_t)(l * 128 + tile0 + r) * 128 + qo);
    u16* dst = s_A + r * ASTRIDE + qo;
#pragma unroll
    for (int i = 0; i < 8; i++) {
      float4 v = src[i];
      ushort4 o;
      o.x = f2bf(v.x); o.y = f2bf(v.y); o.z = f2bf(v.z); o.w = f2bf(v.w);
      *(ushort4*)(dst + i * 4) = o;
    }
  }
  {
    const int4* src = (const int4*)(pw + (size_t)(l * 6 + 4) * 16384);
    int4* dst = (int4*)s_W;
#pragma unroll
    for (int i = 0; i < 8; i++) dst[t + i * 256] = src[t + i * 256];
  }
  __syncthreads();
  f32x4 acc[8];
#pragma unroll
  for (int ct = 0; ct < 8; ct++) acc[ct] = {0.f, 0.f, 0.f, 0.f};
  gemm64(s_A, s_W, w, quad, m16, acc);
#pragma unroll
  for (int ct = 0; ct < 8; ct++)
#pragma unroll
    for (int j = 0; j < 4; j++) {
      int k = tile0 + w * 16 + quad * 4 + j;
      int n = ct * 16 + m16;
      pwc[(size_t)l * 16384 + (k >> 3) * 1024 + n * 8 + (k & 7)] = f2bf(acc[ct][j]);
    }
  if (half == 0 && t < 128) {
    float s = 0.f;
    for (int np = 0; np < 128; np++)
      s += msg_b2[l * 128 + np] * node_w1[(size_t)(l * 256 + 128 + np) * 128 + t];
    vc[l * 128 + t] = s;
  }
  if (l == 0 && half == 1 && t < 128) {
    float up = 0.f, vp = 0.f, uq = 0.f, vq = 0.f;
    for (int k = 0; k < 128; k++) {
      float wa = msg_w1[(size_t)k * 128 + t];          // l=0 msgW1a rows
      float wb = msg_w1[(size_t)(128 + k) * 128 + t];  // l=0 msgW1b rows
      up = fmaf(emb_w[k], wa, up);
      vp = fmaf(emb_b[k], wa, vp);
      uq = fmaf(emb_w[k], wb, uq);
      vq = fmaf(emb_b[k], wb, vq);
    }
    uv[t] = up;
    uv[128 + t] = vp + vq + msg_b1[t];
    uv[256 + t] = uq;
  }
}

// ---- counting sort of edges by target; rank = arrival order per target. ----
__global__ void hist_kernel(const int* __restrict__ eidx, int* __restrict__ deg,
                            int* __restrict__ rnk, int E_) {
  int e = blockIdx.x * 256 + threadIdx.x;
  if (e < E_) rnk[e] = atomicAdd(&deg[eidx[E_ + e]], 1);
}

__global__ void scan1_kernel(const int* __restrict__ deg, int* __restrict__ off,
                             int* __restrict__ bsum, int n) {
  __shared__ int s[256];
  int t = threadIdx.x;
  int i = blockIdx.x * 256 + t;
  int v = (i < n) ? deg[i] : 0;
  s[t] = v;
  for (int d = 1; d < 256; d <<= 1) {
    __syncthreads();
    int x = (t >= d) ? s[t - d] : 0;
    __syncthreads();
    s[t] += x;
  }
  __syncthreads();
  if (i < n) off[i] = s[t] - v;  // block-local exclusive (bsum added at use sites)
  if (t == 255) bsum[blockIdx.x] = s[255];
}

__global__ void scan2_kernel(int* __restrict__ bsum, int nb) {
  __shared__ int s[256];
  int t = threadIdx.x;
  int v = (t < nb) ? bsum[t] : 0;
  s[t] = v;
  for (int d = 1; d < 256; d <<= 1) {
    __syncthreads();
    int x = (t >= d) ? s[t - d] : 0;
    __syncthreads();
    s[t] += x;
  }
  __syncthreads();
  if (t < nb) bsum[t] = s[t] - v;  // exclusive block offsets
}

// scatter edges into target-sorted order — NO atomics (rank precomputed).
// Global offset = off[tg] (block-local) + bsum[tg>>8] (scanned) — scan3 folded in.
// es8[p] = (src | tgt<<15, dist_bits): 8 B/edge (N < 2^15).
__global__ void scatter_kernel(const int* __restrict__ eidx, const float* __restrict__ pos,
                               const int* __restrict__ off, const int* __restrict__ bsum,
                               const int* __restrict__ rnk, int2* __restrict__ es8, int E_) {
  int e = blockIdx.x * 256 + threadIdx.x;
  if (e >= E_) return;
  int sr = eidx[e], tg = eidx[E_ + e];
  float dx = pos[sr * 3 + 0] - pos[tg * 3 + 0];
  float dy = pos[sr * 3 + 1] - pos[tg * 3 + 1];
  float dz = pos[sr * 3 + 2] - pos[tg * 3 + 2];
  float d = dx * dx + dy * dy + dz * dz;
  int p = off[tg] + bsum[tg >> 8] + rnk[e];
  int2 v;
  v.x = sr | (tg << 15);
  v.y = __float_as_int(d);
  es8[p] = v;
}

// edge step with LDS-accumulator close (all targets are block-local).
// R7 version: pads (tg_s=-1) flow through with clamped indices (no branch).
__device__ __forceinline__ void edge_step_lds(
    int tg_s, float dd_s, unsigned qv,
    int& cur_s, float& p0, float& p1, float& s0, float& s1,
    const u16* __restrict__ P, float* s_S, int cp,
    float wd0, float wd1, int tile0) {
  if (tg_s != cur_s) {  // wave-uniform branch
    if (cur_s >= 0) {
      float* dst = &s_S[(cur_s - tile0) * HN + cp];
      atomicAdd(dst, s0);
      atomicAdd(dst + 1, s1);
    }
    cur_s = tg_s; s0 = 0.f; s1 = 0.f;
    int cg = tg_s < 0 ? 0 : tg_s;
    unsigned pv = *(const unsigned*)&P[(size_t)cg * HN + cp];
    p0 = bflo(pv); p1 = bfhi(pv);
  }
  float x0 = p0 + bflo(qv) + dd_s * wd0;
  float x1 = p1 + bfhi(qv) + dd_s * wd1;
  s0 += silu_f(x0);
  s1 += silu_f(x1);
}

// rank-1 edge step (layer 0): P/Q replaced by affine functions of x
__device__ __forceinline__ void edge_step_r1(
    int tg_s, float dd_s, float xs,
    int& cur_s, float& p0, float& p1, float& s0, float& s1,
    const float* s_xt, float* s_S, int cp,
    float wd0, float wd1, float uP0, float uP1, float vP0, float vP1,
    float uQ0, float uQ1, int tile0) {
  if (tg_s != cur_s) {  // wave-uniform branch
    if (cur_s >= 0) {
      float* dst = &s_S[(cur_s - tile0) * HN + cp];
      atomicAdd(dst, s0);
      atomicAdd(dst + 1, s1);
    }
    cur_s = tg_s; s0 = 0.f; s1 = 0.f;
    int ci = tg_s < 0 ? 0 : (tg_s - tile0);
    float xt = s_xt[ci];
    p0 = fmaf(xt, uP0, vP0);
    p1 = fmaf(xt, uP1, vP1);
  }
  float x0 = fmaf(dd_s, wd0, fmaf(xs, uQ0, p0));
  float x1 = fmaf(dd_s, wd1, fmaf(xs, uQ1, p1));
  s0 += silu_f(x0);
  s1 += silu_f(x1);
}

// ---- FUSED layer kernel, LTM=32 (938 blocks) — R7 structure (best measured).
// RANK1 (layer 0): P/Q/h are affine in x — no gathers, no proj kernel.
// Phase 1: wave-autonomous edge ranges into s_S (LDS accumulate), LDS-staged
//   double-buffered es8 pipeline, 8-deep Q prefetch.
// Phase 2: 32x128 MLP in (row-half x col-half) quarters. ----
template <bool FUSE, bool RANK1>
__global__ __launch_bounds__(256) void layer_kernel(
    const u16* __restrict__ P, const u16* __restrict__ Q,
    const u16* __restrict__ hbf, u16* __restrict__ hout,
    const int* __restrict__ off, const int* __restrict__ bsum,
    const int* __restrict__ deg,
    const float* __restrict__ w1d, const int2* __restrict__ es8,
    const u16* __restrict__ pwc, const float* __restrict__ vc,
    const u16* __restrict__ pwn, const float* __restrict__ b1, const float* __restrict__ b2,
    const u16* __restrict__ pw_next, const float* __restrict__ b1_next,
    u16* __restrict__ Pout, u16* __restrict__ Qout,
    const float* __restrict__ xin, const float* __restrict__ uv,
    const float* __restrict__ emb_w, const float* __restrict__ emb_b,
    int nnodes, int E_) {
  __shared__ float s_S[LTM * HN];                   // 16 KB message accumulators
  __shared__ __align__(16) u16 s_A[LTM * ASTRIDE];  // 8.5 KB: ebuf then A-tile
  __shared__ float s_xt[LTM];                       // x of tile nodes (RANK1)
  const int t = threadIdx.x;
  const int w = t >> 6, lane = t & 63, quad = lane >> 4, m16 = lane & 15;
  const int tile0 = blockIdx.x * LTM;
  const int rh = w >> 1;   // row-half (rows rh*16..rh*16+15)
  const int ch = w & 1;    // col-half (cols ch*64..ch*64+63)

  // zero s_S (16KB = 1024 float4); stage x-tile if RANK1
  {
    float4 z = {0.f, 0.f, 0.f, 0.f};
    float4* p4 = (float4*)s_S;
#pragma unroll
    for (int i = 0; i < 4; i++) p4[t + i * 256] = z;
  }
  if constexpr (RANK1) {
    if (t < LTM) {
      int n = tile0 + t;
      s_xt[t] = (n < nnodes) ? xin[n] : 0.f;
    }
  }
  __syncthreads();

  // ================= phase 1: edges =================
  const int cp = lane * 2;
  const float2 wdv = *(const float2*)&w1d[cp];
  const float wd0 = wdv.x, wd1 = wdv.y;
  const int e_lo = off[tile0] + bsum[tile0 >> 8];
  const int e_hi = (tile0 + LTM < nnodes)
                       ? off[tile0 + LTM] + bsum[(tile0 + LTM) >> 8] : E_;
  const int span = e_hi - e_lo;
  const int wstart = e_lo + (span * w) / 4;
  const int wend = e_lo + (span * (w + 1)) / 4;
  const int total = wend - wstart;
  const int nchunks = (total + 63) >> 6;

  int cur_s = -1;
  float s0 = 0.f, s1 = 0.f, p0 = 0.f, p1 = 0.f;

  if constexpr (RANK1) {
    __shared__ float s_xs[4][2][64];
    const float uP0 = uv[cp], uP1 = uv[cp + 1];
    const float vP0 = uv[128 + cp], vP1 = uv[128 + cp + 1];
    const float uQ0 = uv[256 + cp], uQ1 = uv[256 + cp + 1];
    if (nchunks > 0) {
      int2* ebuf = (int2*)(s_A + (w * 8) * ASTRIDE);
      float* xsb = &s_xs[w][0][0];
      // prologue: chunk 0 (es8 + x[src])
      {
        int e = wstart + lane;
        int2 v;
        if (e < wend) v = es8[e];
        else { v.x = (int)0xFFFF8000; v.y = 0; }
        float xl = xin[v.x & 0x7fff];
        ebuf[lane] = v;
        xsb[lane] = xl;
      }
      asm volatile("s_waitcnt lgkmcnt(0)" ::: "memory");
      int tg[8]; float dd[8]; float xs[8];
#pragma unroll
      for (int j = 0; j < 8; j++) {
        int2 v = ebuf[j];
        tg[j] = v.x >> 15; dd[j] = __int_as_float(v.y);
        xs[j] = xsb[j];
      }

      for (int ci = 0; ci < nchunks; ci++) {
        const int cs = (ci & 1), ns = ((ci + 1) & 1);
        const int2* cb = ebuf + cs * 64;
        const float* cx = xsb + cs * 64;
        const int2* nb = ebuf + ns * 64;
        const float* nx = xsb + ns * 64;
        int2 vnext; vnext.x = (int)0xFFFF8000; vnext.y = 0;
        {
          int e = wstart + (ci + 1) * 64 + lane;
          if (ci + 1 < nchunks && e < wend) vnext = es8[e];
        }
        // groups 0..2 (prefetch g+1 from LDS)
#pragma unroll
        for (int g = 0; g < 3; g++) {
          int tgn[8]; float ddn[8]; float xsn[8];
#pragma unroll
          for (int j = 0; j < 8; j++) {
            int2 v = cb[(g + 1) * 8 + j];
            tgn[j] = v.x >> 15; ddn[j] = __int_as_float(v.y);
            xsn[j] = cx[(g + 1) * 8 + j];
          }
#pragma unroll
          for (int j = 0; j < 8; j++) {
            int tg_s = __builtin_amdgcn_readfirstlane(tg[j]);
            edge_step_r1(tg_s, dd[j], xs[j], cur_s, p0, p1, s0, s1, s_xt, s_S, cp,
                         wd0, wd1, uP0, uP1, vP0, vP1, uQ0, uQ1, tile0);
          }
#pragma unroll
          for (int j = 0; j < 8; j++) { tg[j] = tgn[j]; dd[j] = ddn[j]; xs[j] = xsn[j]; }
        }
        // es8 arrived by now; issue the dependent x gather
        float xnext = xin[vnext.x & 0x7fff];
        // groups 3..6
#pragma unroll
        for (int g = 3; g < 7; g++) {
          int tgn[8]; float ddn[8]; float xsn[8];
#pragma unroll
          for (int j = 0; j < 8; j++) {
            int2 v = cb[(g + 1) * 8 + j];
            tgn[j] = v.x >> 15; ddn[j] = __int_as_float(v.y);
            xsn[j] = cx[(g + 1) * 8 + j];
          }
#pragma unroll
          for (int j = 0; j < 8; j++) {
            int tg_s = __builtin_amdgcn_readfirstlane(tg[j]);
            edge_step_r1(tg_s, dd[j], xs[j], cur_s, p0, p1, s0, s1, s_xt, s_S, cp,
                         wd0, wd1, uP0, uP1, vP0, vP1, uQ0, uQ1, tile0);
          }
#pragma unroll
          for (int j = 0; j < 8; j++) { tg[j] = tgn[j]; dd[j] = ddn[j]; xs[j] = xsn[j]; }
        }
        // commit next chunk, then group 7 (prefetching next-chunk group 0)
        ebuf[ns * 64 + lane] = vnext;
        xsb[ns * 64 + lane] = xnext;
        asm volatile("s_waitcnt lgkmcnt(0)" ::: "memory");
        {
          int tgn[8]; float ddn[8]; float xsn[8];
#pragma unroll
          for (int j = 0; j < 8; j++) {
            int2 v = nb[j];
            tgn[j] = v.x >> 15; ddn[j] = __int_as_float(v.y);
            xsn[j] = nx[j];
          }
#pragma unroll
          for (int j = 0; j < 8; j++) {
            int tg_s = __builtin_amdgcn_readfirstlane(tg[j]);
            edge_step_r1(tg_s, dd[j], xs[j], cur_s, p0, p1, s0, s1, s_xt, s_S, cp,
                         wd0, wd1, uP0, uP1, vP0, vP1, uQ0, uQ1, tile0);
          }
#pragma unroll
          for (int j = 0; j < 8; j++) { tg[j] = tgn[j]; dd[j] = ddn[j]; xs[j] = xsn[j]; }
        }
      }
      if (cur_s >= 0) {
        float* dst = &s_S[(cur_s - tile0) * HN + cp];
        atomicAdd(dst, s0);
        atomicAdd(dst + 1, s1);
      }
    }
  } else {
    if (nchunks > 0) {
      int2* ebuf = (int2*)(s_A + (w * 8) * ASTRIDE);
      {
        int e = wstart + lane;
        int2 v;
        if (e < wend) v = es8[e];
        else { v.x = (int)0xFFFF8000; v.y = 0; }
        ebuf[lane] = v;
      }
      asm volatile("s_waitcnt lgkmcnt(0)" ::: "memory");
      int tg[8]; float dd[8]; unsigned qv[8];
#pragma unroll
      for (int j = 0; j < 8; j++) {
        int2 v = ebuf[j];
        tg[j] = v.x >> 15; dd[j] = __int_as_float(v.y);
        qv[j] = *(const unsigned*)&Q[(size_t)(v.x & 0x7fff) * HN + cp];
      }

      for (int ci = 0; ci < nchunks; ci++) {
        const int2* cb = ebuf + (ci & 1) * 64;
        const int2* nb = ebuf + ((ci + 1) & 1) * 64;
        int2 vnext; vnext.x = (int)0xFFFF8000; vnext.y = 0;
        {
          int e = wstart + (ci + 1) * 64 + lane;
          if (ci + 1 < nchunks && e < wend) vnext = es8[e];
        }
#pragma unroll
        for (int g = 0; g < 7; g++) {
          int tgn[8]; float ddn[8]; unsigned qvn[8];
#pragma unroll
          for (int j = 0; j < 8; j++) {
            int2 v = cb[(g + 1) * 8 + j];
            tgn[j] = v.x >> 15; ddn[j] = __int_as_float(v.y);
            qvn[j] = *(const unsigned*)&Q[(size_t)(v.x & 0x7fff) * HN + cp];
          }
#pragma unroll
          for (int j = 0; j < 8; j++) {
            int tg_s = __builtin_amdgcn_readfirstlane(tg[j]);
            edge_step_lds(tg_s, dd[j], qv[j], cur_s, p0, p1, s0, s1, P, s_S, cp, wd0, wd1, tile0);
          }
#pragma unroll
          for (int j = 0; j < 8; j++) { tg[j] = tgn[j]; dd[j] = ddn[j]; qv[j] = qvn[j]; }
        }
        ebuf[((ci + 1) & 1) * 64 + lane] = vnext;
        asm volatile("s_waitcnt lgkmcnt(0)" ::: "memory");
        {
          int tgn[8]; float ddn[8]; unsigned qvn[8];
#pragma unroll
          for (int j = 0; j < 8; j++) {
            int2 v = nb[j];
            tgn[j] = v.x >> 15; ddn[j] = __int_as_float(v.y);
            qvn[j] = *(const unsigned*)&Q[(size_t)(v.x & 0x7fff) * HN + cp];
          }
#pragma unroll
          for (int j = 0; j < 8; j++) {
            int tg_s = __builtin_amdgcn_readfirstlane(tg[j]);
            edge_step_lds(tg_s, dd[j], qv[j], cur_s, p0, p1, s0, s1, P, s_S, cp, wd0, wd1, tile0);
          }
#pragma unroll
          for (int j = 0; j < 8; j++) { tg[j] = tgn[j]; dd[j] = ddn[j]; qv[j] = qvn[j]; }
        }
      }
      if (cur_s >= 0) {
        float* dst = &s_S[(cur_s - tile0) * HN + cp];
        atomicAdd(dst, s0);
        atomicAdd(dst + 1, s1);
      }
    }
  }
  __syncthreads();  // s_S complete; s_A free for A-tile

  // ================= phase 2: node MLP (quarter-split) =================
  // stage s_S -> s_A bf16: each wave stages 8 rows (rows w*8..w*8+7)
  {
    int srow = w * 8 + (lane >> 3);
    int scol = (lane & 7) * 16;
    const float4* src = (const float4*)&s_S[srow * HN + scol];
    u16* dst = s_A + srow * ASTRIDE + scol;
#pragma unroll
    for (int i = 0; i < 4; i++) {
      float4 v = src[i];
      ushort4 o;
      o.x = f2bf(v.x); o.y = f2bf(v.y); o.z = f2bf(v.z); o.w = f2bf(v.w);
      *(ushort4*)(dst + i * 4) = o;
    }
  }
  __syncthreads();  // cross-wave A reads

  float bb1[4], vcr[4], bb2[4], bbn[4];
#pragma unroll
  for (int ct = 0; ct < 4; ct++) {
    int c = (ch * 4 + ct) * 16 + m16;
    bb1[ct] = b1[c];
    vcr[ct] = vc[c];
    bb2[ct] = b2[c];
    bbn[ct] = FUSE ? b1_next[c] : 0.f;
  }
  int nodem = tile0 + rh * 16 + m16;
  if (nodem >= nnodes) nodem = nnodes - 1;

  f32x4 acc[4];
#pragma unroll
  for (int ct = 0; ct < 4; ct++) acc[ct] = {0.f, 0.f, 0.f, 0.f};
  gemm32_gb(s_A, pwc, rh, ch, quad, m16, acc);         // S@Wc (quarter)

  bf16x8 aH[4];
  if constexpr (RANK1) {
    float xv = s_xt[rh * 16 + m16];
#pragma unroll
    for (int ks = 0; ks < 4; ks++) {
      u16 hv[8];
#pragma unroll
      for (int i = 0; i < 8; i++) {
        int c = ks * 32 + quad * 8 + i;
        hv[i] = f2bf(fmaf(xv, emb_w[c], emb_b[c]));
      }
      aH[ks] = *(bf16x8*)hv;
    }
  } else {
#pragma unroll
    for (int ks = 0; ks < 4; ks++)
      aH[ks] = *(const bf16x8*)&hbf[(size_t)nodem * HN + ks * 32 + quad * 8];
  }
  gemm32_ra_gb(aH, pwn, ch, quad, m16, acc);           // + h@W1a

  // silu(acc + deg*vc + b1) -> own quarter of s_A
  {
    float degv[4];
#pragma unroll
    for (int j = 0; j < 4; j++) {
      int n = tile0 + rh * 16 + quad * 4 + j;
      if (n >= nnodes) n = nnodes - 1;
      degv[j] = (float)deg[n];
    }
#pragma unroll
    for (int ct = 0; ct < 4; ct++)
#pragma unroll
      for (int j = 0; j < 4; j++) {
        int row = rh * 16 + quad * 4 + j;
        float xv = acc[ct][j] + bb1[ct] + degv[j] * vcr[ct];
        s_A[row * ASTRIDE + (ch * 4 + ct) * 16 + m16] = f2bf(silu_f(xv));
      }
  }
  __syncthreads();  // full rows needed by both col-half waves

#pragma unroll
  for (int ct = 0; ct < 4; ct++) acc[ct] = {0.f, 0.f, 0.f, 0.f};
  gemm32_gb(s_A, pwn + 32768, rh, ch, quad, m16, acc); // hidden@W2n

  // h' = acc + b2: store hout quarter; FUSE: also into s_A quarter
#pragma unroll
  for (int ct = 0; ct < 4; ct++)
#pragma unroll
    for (int j = 0; j < 4; j++) {
      int row = rh * 16 + quad * 4 + j;
      int n = tile0 + row;
      u16 hv = f2bf(acc[ct][j] + bb2[ct]);
      if (n < nnodes) hout[(size_t)n * HN + (ch * 4 + ct) * 16 + m16] = hv;
      if (FUSE) s_A[row * ASTRIDE + (ch * 4 + ct) * 16 + m16] = hv;
    }

  if (FUSE) {
    __syncthreads();  // full h' rows for both col-halves
#pragma unroll
    for (int ct = 0; ct < 4; ct++) acc[ct] = {0.f, 0.f, 0.f, 0.f};
    gemm32_gb(s_A, pw_next, rh, ch, quad, m16, acc);   // h'@msgW1a'
#pragma unroll
    for (int ct = 0; ct < 4; ct++)
#pragma unroll
      for (int j = 0; j < 4; j++) {
        int n = tile0 + rh * 16 + quad * 4 + j;
        if (n < nnodes) Pout[(size_t)n * HN + (ch * 4 + ct) * 16 + m16] = f2bf(acc[ct][j] + bbn[ct]);
      }
#pragma unroll
    for (int ct = 0; ct < 4; ct++) acc[ct] = {0.f, 0.f, 0.f, 0.f};
    gemm32_gb(s_A, pw_next + 16384, rh, ch, quad, m16, acc);  // h'@msgW1b'
#pragma unroll
    for (int ct = 0; ct < 4; ct++)
#pragma unroll
      for (int j = 0; j < 4; j++) {
        int n = tile0 + rh * 16 + quad * 4 + j;
        if (n < nnodes) Qout[(size_t)n * HN + (ch * 4 + ct) * 16 + m16] = f2bf(acc[ct][j]);
      }
  }
}

// ---- fused pool+out: one block per graph (batch sorted -> contiguous range
// via binary search). LDS accumulation replaces global atomics; wave 0 runs
// the output MLP. ----
__global__ __launch_bounds__(256) void poolout_kernel(
    const u16* __restrict__ h, const int* __restrict__ batch,
    const float* __restrict__ w1, const float* __restrict__ b1,
    const float* __restrict__ w2, const float* __restrict__ b2,
    float* __restrict__ out, int N) {
  __shared__ float sg[128];
  const int gi = blockIdx.x;
  const int t = threadIdx.x;
  // [start,end) = rows of graph gi
  int lo = 0, hi = N;
  while (lo < hi) { int mid = (lo + hi) >> 1; if (batch[mid] < gi) lo = mid + 1; else hi = mid; }
  const int start = lo;
  hi = N;
  while (lo < hi) { int mid = (lo + hi) >> 1; if (batch[mid] < gi + 1) lo = mid + 1; else hi = mid; }
  const int end = lo;

  const int cp = (t & 63) * 2;  // colpair
  const int rg = t >> 6;        // rowgroup (stride 4)
  if (rg == 0) { sg[cp] = 0.f; sg[cp + 1] = 0.f; }
  __syncthreads();
  float s0 = 0.f, s1 = 0.f;
  for (int r = start + rg; r < end; r += 4) {
    unsigned v = *(const unsigned*)&h[(size_t)r * HN + cp];
    s0 += bf2f((u16)(v & 0xffffu));
    s1 += bf2f((u16)(v >> 16));
  }
  atomicAdd(&sg[cp], s0);
  atomicAdd(&sg[cp + 1], s1);
  __syncthreads();

  if (t < 64) {
    const int c = t & 31, kh = t >> 5;
    float s = 0.f;
    for (int k = kh * 64; k < kh * 64 + 64; k++)
      s += sg[k] * w1[k * 32 + c];
    s += __shfl_down(s, 32);
    float r = 0.f;
    if (kh == 0) r = silu_f(s + b1[c]) * w2[c];
    r += __shfl_down(r, 16);
    r += __shfl_down(r, 8);
    r += __shfl_down(r, 4);
    r += __shfl_down(r, 2);
    r += __shfl_down(r, 1);
    if (t == 0) out[gi] = r + b2[0];
  }
}

extern "C" void kernel_launch(void* const* d_in, const int* in_sizes, int n_in,
                              void* d_out, int out_size, void* d_ws, size_t ws_size,
                              hipStream_t stream) {
  const float* x = (const float*)d_in[0];
  const float* pos = (const float*)d_in[1];
  const int* eidx = (const int*)d_in[2];
  const int* batch = (const int*)d_in[3];
  const float* emb_w = (const float*)d_in[4];
  const float* emb_b = (const float*)d_in[5];
  const float* msg_w1 = (const float*)d_in[6];
  const float* msg_b1 = (const float*)d_in[7];
  const float* msg_w2 = (const float*)d_in[8];
  const float* msg_b2 = (const float*)d_in[9];
  const float* node_w1 = (const float*)d_in[10];
  const float* node_b1 = (const float*)d_in[11];
  const float* node_w2 = (const float*)d_in[12];
  const float* node_b2 = (const float*)d_in[13];
  const float* out_w1 = (const float*)d_in[14];
  const float* out_b1 = (const float*)d_in[15];
  const float* out_w2 = (const float*)d_in[16];
  const float* out_b2 = (const float*)d_in[17];
  float* outp = (float*)d_out;

  const int N = 30000, E = 600000, G = 64;
  const size_t NH = (size_t)N * HN;

  u16* hA = (u16*)d_ws;                       // N*128 bf16
  u16* hB = hA + NH;                          // N*128 bf16
  u16* Pa = hB + NH;                          // N*128 bf16 (P ping)
  u16* Qa = Pa + NH;                          // N*128 bf16 (Q ping)
  u16* Pb = Qa + NH;                          // N*128 bf16 (P pong)
  u16* Qb = Pb + NH;                          // N*128 bf16 (Q pong)
  int2* es8 = (int2*)(Qb + NH);               // E int2 (src|tgt<<15, dist)
  int* deg = (int*)(es8 + E);                 // N
  int* off = deg + N;                         // N (block-local exclusive)
  int* bsum = off + N;                        // 128 (scanned block sums)
  u16* pw = (u16*)(bsum + 128);               // 4*6*16384 bf16
  u16* pwc = pw + (size_t)4 * 6 * 16384;      // 4*16384 bf16 (folded Wc)
  float* vcb = (float*)(pwc + (size_t)4 * 16384);  // 4*128 f32
  float* uvb = vcb + 4 * 128;                 // 3*128 f32 (layer-0 rank-1 vecs)
  int* rnk = (int*)Pb;                        // E ints, aliases P-pong (dead before layer0)

  const int NB = (N + 255) / 256;
  const int NLB = (N + LTM - 1) / LTM;

  // pack + zero deg (replaces memset)
  pack_weights<<<(4 * 6 * 16384 + 255) / 256, 256, 0, stream>>>(
      msg_w1, msg_w2, node_w1, node_w2, pw, deg, N);
  fold_kernel<<<8, 256, 0, stream>>>(msg_w2, node_w1, msg_b2, pw, pwc, vcb,
                                     msg_w1, emb_w, emb_b, msg_b1, uvb);

  // counting sort by target (rank precomputed in hist -> atomic-free scatter;
  // scan3 folded into scatter/layer via off+bsum addressing)
  hist_kernel<<<(E + 255) / 256, 256, 0, stream>>>(eidx, deg, rnk, E);
  scan1_kernel<<<NB, 256, 0, stream>>>(deg, off, bsum, N);
  scan2_kernel<<<1, 256, 0, stream>>>(bsum, NB);
  scatter_kernel<<<(E + 255) / 256, 256, 0, stream>>>(eidx, pos, off, bsum, rnk, es8, E);

  // NOTE: no proj kernel — layer 0 uses the rank-1 path (h0 = x*emb_w + emb_b)

  for (int l = 0; l < 4; l++) {
    const u16* pwl = pw + (size_t)(l * 6) * 16384;
    const float* w1d = msg_w1 + (size_t)(l * 257 + 256) * 128;
    u16* hin = (l & 1) ? hA : hB;   // l0: unused
    u16* hot = (l & 1) ? hB : hA;   // l0->hA, l1->hB, l2->hA, l3->hB
    u16* Pin = (l & 1) ? Pb : Pa;   // l1 reads Pb (l0 out), l2 reads Pa, l3 reads Pb
    u16* Qin = (l & 1) ? Qb : Qa;
    u16* Pot = (l & 1) ? Pa : Pb;
    u16* Qot = (l & 1) ? Qa : Qb;
    if (l == 0) {
      layer_kernel<true, true><<<NLB, 256, 0, stream>>>(
          Pin, Qin, hin, hot, off, bsum, deg, w1d, es8,
          pwc + (size_t)l * 16384, vcb + l * 128,
          pwl + 3 * 16384, node_b1 + l * 128, node_b2 + l * 128,
          pw + (size_t)((l + 1) * 6) * 16384, msg_b1 + (l + 1) * 128, Pot, Qot,
          x, uvb, emb_w, emb_b, N, E);
    } else if (l < 3) {
      layer_kernel<true, false><<<NLB, 256, 0, stream>>>(
          Pin, Qin, hin, hot, off, bsum, deg, w1d, es8,
          pwc + (size_t)l * 16384, vcb + l * 128,
          pwl + 3 * 16384, node_b1 + l * 128, node_b2 + l * 128,
          pw + (size_t)((l + 1) * 6) * 16384, msg_b1 + (l + 1) * 128, Pot, Qot,
          x, uvb, emb_w, emb_b, N, E);
    } else {
      layer_kernel<false, false><<<NLB, 256, 0, stream>>>(
          Pin, Qin, hin, hot, off, bsum, deg, w1d, es8,
          pwc + (size_t)l * 16384, vcb + l * 128,
          pwl + 3 * 16384, node_b1 + l * 128, node_b2 + l * 128,
          nullptr, nullptr, nullptr, nullptr,
          x, uvb, emb_w, emb_b, N, E);
    }
  }

  poolout_kernel<<<G, 256, 0, stream>>>(hB, batch, out_w1, out_b1, out_w2, out_b2,
                                        outp, N);
}

// Round 13
// 382.210 us; speedup vs baseline: 1.0421x; 1.0252x over previous
//
#include <hip/hip_runtime.h>

typedef unsigned short u16;
typedef __bf16 bf16x8 __attribute__((ext_vector_type(8)));
typedef float f32x4 __attribute__((ext_vector_type(4)));

#define HN 128
#define TM 64
#define LTM 32        // layer-kernel tile (32 nodes/block, 938 blocks)
#define ASTRIDE 136   // 128 + 8 pad (u16), rows 16B-aligned

__device__ __forceinline__ u16 f2bf(float f) {
  union { float f; unsigned u; } v; v.f = f;
  unsigned r = v.u + 0x7fffu + ((v.u >> 16) & 1u);
  return (u16)(r >> 16);
}
__device__ __forceinline__ float bf2f(u16 v) {
  union { unsigned u; float f; } x; x.u = ((unsigned)v) << 16; return x.f;
}
__device__ __forceinline__ float bflo(unsigned v) {
  union { unsigned u; float f; } x; x.u = v << 16; return x.f;
}
__device__ __forceinline__ float bfhi(unsigned v) {
  union { unsigned u; float f; } x; x.u = v & 0xffff0000u; return x.f;
}
// fast silu: x * rcp(1 + exp2(-log2e*x)) — v_exp_f32/v_rcp_f32, ~1 ulp
__device__ __forceinline__ float silu_f(float x) {
  float e = __builtin_amdgcn_exp2f(-1.442695041f * x);
  return x * __builtin_amdgcn_rcpf(1.f + e);
}

// ---- pack weights into MFMA B-fragment layout: P[kg][n][8], kg=k/8 ----
// mats per layer: 0=msgW1a 1=msgW1b 2=msgW2 3=nodeW1a 4=nodeW1b 5=nodeW2
// Also zeroes deg[N] and g[G*HN].
__global__ void pack_weights(const float* __restrict__ msg_w1, const float* __restrict__ msg_w2,
                             const float* __restrict__ node_w1, const float* __restrict__ node_w2,
                             u16* __restrict__ pw, int* __restrict__ deg,
                             float* __restrict__ g, int N_, int GH) {
  int id = blockIdx.x * 256 + threadIdx.x;
  if (id < N_) deg[id] = 0;
  if (id < GH) g[id] = 0.f;
  if (id >= 4 * 6 * 16384) return;
  int l = id / (6 * 16384);
  int rem = id % (6 * 16384);
  int m = rem / 16384;
  int e = rem % 16384;
  int kg = e >> 10;
  int n = (e >> 3) & 127;
  int j = e & 7;
  int k = kg * 8 + j;
  float v = 0.f;
  switch (m) {
    case 0: v = msg_w1[(l * 257 + k) * 128 + n]; break;
    case 1: v = msg_w1[(l * 257 + 128 + k) * 128 + n]; break;
    case 2: v = msg_w2[(l * 128 + k) * 128 + n]; break;
    case 3: v = node_w1[(l * 256 + k) * 128 + n]; break;
    case 4: v = node_w1[(l * 256 + 128 + k) * 128 + n]; break;
    case 5: v = node_w2[(l * 128 + k) * 128 + n]; break;
  }
  pw[id] = f2bf(v);
}

// A from LDS band (rows w*16..w*16+15), B from LDS (64-row tile kernels)
__device__ __forceinline__ void gemm64(const u16* s_A, const u16* s_W,
                                       int w, int quad, int m16, f32x4 acc[8]) {
#pragma unroll
  for (int ks = 0; ks < 4; ks++) {
    bf16x8 a = *(const bf16x8*)&s_A[(w * 16 + m16) * ASTRIDE + ks * 32 + quad * 8];
#pragma unroll
    for (int ct = 0; ct < 8; ct++) {
      bf16x8 b = *(const bf16x8*)&s_W[(ks * 4 + quad) * 1024 + (ct * 16 + m16) * 8];
      acc[ct] = __builtin_amdgcn_mfma_f32_16x16x32_bf16(a, b, acc[ct], 0, 0, 0);
    }
  }
}

// quarter-gemm: A rows rh*16.., B col-half ch (ct' = ch*4+ct); B from global (L2)
__device__ __forceinline__ void gemm32_gb(const u16* s_A, const u16* __restrict__ gW,
                                          int rh, int ch, int quad, int m16, f32x4 acc[4]) {
#pragma unroll
  for (int ks = 0; ks < 4; ks++) {
    bf16x8 a = *(const bf16x8*)&s_A[(rh * 16 + m16) * ASTRIDE + ks * 32 + quad * 8];
#pragma unroll
    for (int ct = 0; ct < 4; ct++) {
      bf16x8 b = *(const bf16x8*)&gW[(ks * 4 + quad) * 1024 + ((ch * 4 + ct) * 16 + m16) * 8];
      acc[ct] = __builtin_amdgcn_mfma_f32_16x16x32_bf16(a, b, acc[ct], 0, 0, 0);
    }
  }
}

// quarter-gemm, A from registers
__device__ __forceinline__ void gemm32_ra_gb(const bf16x8 aH[4], const u16* __restrict__ gW,
                                             int ch, int quad, int m16, f32x4 acc[4]) {
#pragma unroll
  for (int ks = 0; ks < 4; ks++) {
#pragma unroll
    for (int ct = 0; ct < 4; ct++) {
      bf16x8 b = *(const bf16x8*)&gW[(ks * 4 + quad) * 1024 + ((ch * 4 + ct) * 16 + m16) * 8];
      acc[ct] = __builtin_amdgcn_mfma_f32_16x16x32_bf16(aH[ks], b, acc[ct], 0, 0, 0);
    }
  }
}

// ---- fold: Wc = msgW2 @ nodeW1b (bf16, B-frag packed), vc = msg_b2 @ nodeW1b.
// Block (l=0,half=1) also computes layer-0 rank-1 vectors:
//   uv = [uP | vP+vQ+b1 | uQ], uP=emb_w@msgW1a etc. ----
__global__ __launch_bounds__(256) void fold_kernel(
    const float* __restrict__ msg_w2, const float* __restrict__ node_w1,
    const float* __restrict__ msg_b2, const u16* __restrict__ pw,
    u16* __restrict__ pwc, float* __restrict__ vc,
    const float* __restrict__ msg_w1, const float* __restrict__ emb_w,
    const float* __restrict__ emb_b, const float* __restrict__ msg_b1,
    float* __restrict__ uv) {
  __shared__ __align__(16) u16 s_A[TM * ASTRIDE];
  __shared__ __align__(16) u16 s_W[16384];
  const int t = threadIdx.x;
  const int w = t >> 6, lane = t & 63, quad = lane >> 4, m16 = lane & 15;
  const int b = blockIdx.x, l = b >> 1, half = b & 1;
  const int tile0 = half * 64;

  {
    int r = t >> 2, qo = (t & 3) * 32;
    const float4* src = (const float4*)(msg_w2 + (size_t)(l * 128 + tile0 + r) * 128 + qo);
    u16* dst = s_A + r * ASTRIDE + qo;
#pragma unroll
    for (int i = 0; i < 8; i++) {
      float4 v = src[i];
      ushort4 o;
      o.x = f2bf(v.x); o.y = f2bf(v.y); o.z = f2bf(v.z); o.w = f2bf(v.w);
      *(ushort4*)(dst + i * 4) = o;
    }
  }
  {
    const int4* src = (const int4*)(pw + (size_t)(l * 6 + 4) * 16384);
    int4* dst = (int4*)s_W;
#pragma unroll
    for (int i = 0; i < 8; i++) dst[t + i * 256] = src[t + i * 256];
  }
  __syncthreads();
  f32x4 acc[8];
#pragma unroll
  for (int ct = 0; ct < 8; ct++) acc[ct] = {0.f, 0.f, 0.f, 0.f};
  gemm64(s_A, s_W, w, quad, m16, acc);
#pragma unroll
  for (int ct = 0; ct < 8; ct++)
#pragma unroll
    for (int j = 0; j < 4; j++) {
      int k = tile0 + w * 16 + quad * 4 + j;
      int n = ct * 16 + m16;
      pwc[(size_t)l * 16384 + (k >> 3) * 1024 + n * 8 + (k & 7)] = f2bf(acc[ct][j]);
    }
  if (half == 0 && t < 128) {
    float s = 0.f;
    for (int np = 0; np < 128; np++)
      s += msg_b2[l * 128 + np] * node_w1[(size_t)(l * 256 + 128 + np) * 128 + t];
    vc[l * 128 + t] = s;
  }
  if (l == 0 && half == 1 && t < 128) {
    float up = 0.f, vp = 0.f, uq = 0.f, vq = 0.f;
    for (int k = 0; k < 128; k++) {
      float wa = msg_w1[(size_t)k * 128 + t];          // l=0 msgW1a rows
      float wb = msg_w1[(size_t)(128 + k) * 128 + t];  // l=0 msgW1b rows
      up = fmaf(emb_w[k], wa, up);
      vp = fmaf(emb_b[k], wa, vp);
      uq = fmaf(emb_w[k], wb, uq);
      vq = fmaf(emb_b[k], wb, vq);
    }
    uv[t] = up;
    uv[128 + t] = vp + vq + msg_b1[t];
    uv[256 + t] = uq;
  }
}

// ---- counting sort of edges by target; rank = arrival order per target. ----
__global__ void hist_kernel(const int* __restrict__ eidx, int* __restrict__ deg,
                            int* __restrict__ rnk, int E_) {
  int e = blockIdx.x * 256 + threadIdx.x;
  if (e < E_) rnk[e] = atomicAdd(&deg[eidx[E_ + e]], 1);
}

__global__ void scan1_kernel(const int* __restrict__ deg, int* __restrict__ off,
                             int* __restrict__ bsum, int n) {
  __shared__ int s[256];
  int t = threadIdx.x;
  int i = blockIdx.x * 256 + t;
  int v = (i < n) ? deg[i] : 0;
  s[t] = v;
  for (int d = 1; d < 256; d <<= 1) {
    __syncthreads();
    int x = (t >= d) ? s[t - d] : 0;
    __syncthreads();
    s[t] += x;
  }
  __syncthreads();
  if (i < n) off[i] = s[t] - v;  // block-local exclusive (bsum added at use sites)
  if (t == 255) bsum[blockIdx.x] = s[255];
}

__global__ void scan2_kernel(int* __restrict__ bsum, int nb) {
  __shared__ int s[256];
  int t = threadIdx.x;
  int v = (t < nb) ? bsum[t] : 0;
  s[t] = v;
  for (int d = 1; d < 256; d <<= 1) {
    __syncthreads();
    int x = (t >= d) ? s[t - d] : 0;
    __syncthreads();
    s[t] += x;
  }
  __syncthreads();
  if (t < nb) bsum[t] = s[t] - v;  // exclusive block offsets
}

// scatter edges into target-sorted order — NO atomics (rank precomputed).
// Global offset = off[tg] (block-local) + bsum[tg>>8] (scanned) — scan3 folded in.
// es8[p] = (src | tgt<<15, dist_bits): 8 B/edge (N < 2^15).
__global__ void scatter_kernel(const int* __restrict__ eidx, const float* __restrict__ pos,
                               const int* __restrict__ off, const int* __restrict__ bsum,
                               const int* __restrict__ rnk, int2* __restrict__ es8, int E_) {
  int e = blockIdx.x * 256 + threadIdx.x;
  if (e >= E_) return;
  int sr = eidx[e], tg = eidx[E_ + e];
  float dx = pos[sr * 3 + 0] - pos[tg * 3 + 0];
  float dy = pos[sr * 3 + 1] - pos[tg * 3 + 1];
  float dz = pos[sr * 3 + 2] - pos[tg * 3 + 2];
  float d = dx * dx + dy * dy + dz * dz;
  int p = off[tg] + bsum[tg >> 8] + rnk[e];
  int2 v;
  v.x = sr | (tg << 15);
  v.y = __float_as_int(d);
  es8[p] = v;
}

// edge step with LDS-accumulator close (all targets are block-local).
// R7 version: pads (tg_s=-1) flow through with clamped indices (no branch).
__device__ __forceinline__ void edge_step_lds(
    int tg_s, float dd_s, unsigned qv,
    int& cur_s, float& p0, float& p1, float& s0, float& s1,
    const u16* __restrict__ P, float* s_S, int cp,
    float wd0, float wd1, int tile0) {
  if (tg_s != cur_s) {  // wave-uniform branch
    if (cur_s >= 0) {
      float* dst = &s_S[(cur_s - tile0) * HN + cp];
      atomicAdd(dst, s0);
      atomicAdd(dst + 1, s1);
    }
    cur_s = tg_s; s0 = 0.f; s1 = 0.f;
    int cg = tg_s < 0 ? 0 : tg_s;
    unsigned pv = *(const unsigned*)&P[(size_t)cg * HN + cp];
    p0 = bflo(pv); p1 = bfhi(pv);
  }
  float x0 = p0 + bflo(qv) + dd_s * wd0;
  float x1 = p1 + bfhi(qv) + dd_s * wd1;
  s0 += silu_f(x0);
  s1 += silu_f(x1);
}

// rank-1 edge step (layer 0): P/Q replaced by affine functions of x
__device__ __forceinline__ void edge_step_r1(
    int tg_s, float dd_s, float xs,
    int& cur_s, float& p0, float& p1, float& s0, float& s1,
    const float* s_xt, float* s_S, int cp,
    float wd0, float wd1, float uP0, float uP1, float vP0, float vP1,
    float uQ0, float uQ1, int tile0) {
  if (tg_s != cur_s) {  // wave-uniform branch
    if (cur_s >= 0) {
      float* dst = &s_S[(cur_s - tile0) * HN + cp];
      atomicAdd(dst, s0);
      atomicAdd(dst + 1, s1);
    }
    cur_s = tg_s; s0 = 0.f; s1 = 0.f;
    int ci = tg_s < 0 ? 0 : (tg_s - tile0);
    float xt = s_xt[ci];
    p0 = fmaf(xt, uP0, vP0);
    p1 = fmaf(xt, uP1, vP1);
  }
  float x0 = fmaf(dd_s, wd0, fmaf(xs, uQ0, p0));
  float x1 = fmaf(dd_s, wd1, fmaf(xs, uQ1, p1));
  s0 += silu_f(x0);
  s1 += silu_f(x1);
}

// ---- FUSED layer kernel, LTM=32 (938 blocks) — R7 structure (best measured).
// RANK1 (layer 0): P/Q/h are affine in x — no gathers, no proj kernel.
// Phase 1: wave-autonomous edge ranges into s_S (LDS accumulate), LDS-staged
//   double-buffered es8 pipeline, 8-deep Q prefetch.
// Phase 2: 32x128 MLP in (row-half x col-half) quarters. ----
template <bool FUSE, bool RANK1>
__global__ __launch_bounds__(256) void layer_kernel(
    const u16* __restrict__ P, const u16* __restrict__ Q,
    const u16* __restrict__ hbf, u16* __restrict__ hout,
    const int* __restrict__ off, const int* __restrict__ bsum,
    const int* __restrict__ deg,
    const float* __restrict__ w1d, const int2* __restrict__ es8,
    const u16* __restrict__ pwc, const float* __restrict__ vc,
    const u16* __restrict__ pwn, const float* __restrict__ b1, const float* __restrict__ b2,
    const u16* __restrict__ pw_next, const float* __restrict__ b1_next,
    u16* __restrict__ Pout, u16* __restrict__ Qout,
    const float* __restrict__ xin, const float* __restrict__ uv,
    const float* __restrict__ emb_w, const float* __restrict__ emb_b,
    int nnodes, int E_) {
  __shared__ float s_S[LTM * HN];                   // 16 KB message accumulators
  __shared__ __align__(16) u16 s_A[LTM * ASTRIDE];  // 8.5 KB: ebuf then A-tile
  __shared__ float s_xt[LTM];                       // x of tile nodes (RANK1)
  const int t = threadIdx.x;
  const int w = t >> 6, lane = t & 63, quad = lane >> 4, m16 = lane & 15;
  const int tile0 = blockIdx.x * LTM;
  const int rh = w >> 1;   // row-half (rows rh*16..rh*16+15)
  const int ch = w & 1;    // col-half (cols ch*64..ch*64+63)

  // zero s_S (16KB = 1024 float4); stage x-tile if RANK1
  {
    float4 z = {0.f, 0.f, 0.f, 0.f};
    float4* p4 = (float4*)s_S;
#pragma unroll
    for (int i = 0; i < 4; i++) p4[t + i * 256] = z;
  }
  if constexpr (RANK1) {
    if (t < LTM) {
      int n = tile0 + t;
      s_xt[t] = (n < nnodes) ? xin[n] : 0.f;
    }
  }
  __syncthreads();

  // ================= phase 1: edges =================
  const int cp = lane * 2;
  const float2 wdv = *(const float2*)&w1d[cp];
  const float wd0 = wdv.x, wd1 = wdv.y;
  const int e_lo = off[tile0] + bsum[tile0 >> 8];
  const int e_hi = (tile0 + LTM < nnodes)
                       ? off[tile0 + LTM] + bsum[(tile0 + LTM) >> 8] : E_;
  const int span = e_hi - e_lo;
  const int wstart = e_lo + (span * w) / 4;
  const int wend = e_lo + (span * (w + 1)) / 4;
  const int total = wend - wstart;
  const int nchunks = (total + 63) >> 6;

  int cur_s = -1;
  float s0 = 0.f, s1 = 0.f, p0 = 0.f, p1 = 0.f;

  if constexpr (RANK1) {
    __shared__ float s_xs[4][2][64];
    const float uP0 = uv[cp], uP1 = uv[cp + 1];
    const float vP0 = uv[128 + cp], vP1 = uv[128 + cp + 1];
    const float uQ0 = uv[256 + cp], uQ1 = uv[256 + cp + 1];
    if (nchunks > 0) {
      int2* ebuf = (int2*)(s_A + (w * 8) * ASTRIDE);
      float* xsb = &s_xs[w][0][0];
      // prologue: chunk 0 (es8 + x[src])
      {
        int e = wstart + lane;
        int2 v;
        if (e < wend) v = es8[e];
        else { v.x = (int)0xFFFF8000; v.y = 0; }
        float xl = xin[v.x & 0x7fff];
        ebuf[lane] = v;
        xsb[lane] = xl;
      }
      asm volatile("s_waitcnt lgkmcnt(0)" ::: "memory");
      int tg[8]; float dd[8]; float xs[8];
#pragma unroll
      for (int j = 0; j < 8; j++) {
        int2 v = ebuf[j];
        tg[j] = v.x >> 15; dd[j] = __int_as_float(v.y);
        xs[j] = xsb[j];
      }

      for (int ci = 0; ci < nchunks; ci++) {
        const int cs = (ci & 1), ns = ((ci + 1) & 1);
        const int2* cb = ebuf + cs * 64;
        const float* cx = xsb + cs * 64;
        const int2* nb = ebuf + ns * 64;
        const float* nx = xsb + ns * 64;
        int2 vnext; vnext.x = (int)0xFFFF8000; vnext.y = 0;
        {
          int e = wstart + (ci + 1) * 64 + lane;
          if (ci + 1 < nchunks && e < wend) vnext = es8[e];
        }
        // groups 0..2 (prefetch g+1 from LDS)
#pragma unroll
        for (int g = 0; g < 3; g++) {
          int tgn[8]; float ddn[8]; float xsn[8];
#pragma unroll
          for (int j = 0; j < 8; j++) {
            int2 v = cb[(g + 1) * 8 + j];
            tgn[j] = v.x >> 15; ddn[j] = __int_as_float(v.y);
            xsn[j] = cx[(g + 1) * 8 + j];
          }
#pragma unroll
          for (int j = 0; j < 8; j++) {
            int tg_s = __builtin_amdgcn_readfirstlane(tg[j]);
            edge_step_r1(tg_s, dd[j], xs[j], cur_s, p0, p1, s0, s1, s_xt, s_S, cp,
                         wd0, wd1, uP0, uP1, vP0, vP1, uQ0, uQ1, tile0);
          }
#pragma unroll
          for (int j = 0; j < 8; j++) { tg[j] = tgn[j]; dd[j] = ddn[j]; xs[j] = xsn[j]; }
        }
        // es8 arrived by now; issue the dependent x gather
        float xnext = xin[vnext.x & 0x7fff];
        // groups 3..6
#pragma unroll
        for (int g = 3; g < 7; g++) {
          int tgn[8]; float ddn[8]; float xsn[8];
#pragma unroll
          for (int j = 0; j < 8; j++) {
            int2 v = cb[(g + 1) * 8 + j];
            tgn[j] = v.x >> 15; ddn[j] = __int_as_float(v.y);
            xsn[j] = cx[(g + 1) * 8 + j];
          }
#pragma unroll
          for (int j = 0; j < 8; j++) {
            int tg_s = __builtin_amdgcn_readfirstlane(tg[j]);
            edge_step_r1(tg_s, dd[j], xs[j], cur_s, p0, p1, s0, s1, s_xt, s_S, cp,
                         wd0, wd1, uP0, uP1, vP0, vP1, uQ0, uQ1, tile0);
          }
#pragma unroll
          for (int j = 0; j < 8; j++) { tg[j] = tgn[j]; dd[j] = ddn[j]; xs[j] = xsn[j]; }
        }
        // commit next chunk, then group 7 (prefetching next-chunk group 0)
        ebuf[ns * 64 + lane] = vnext;
        xsb[ns * 64 + lane] = xnext;
        asm volatile("s_waitcnt lgkmcnt(0)" ::: "memory");
        {
          int tgn[8]; float ddn[8]; float xsn[8];
#pragma unroll
          for (int j = 0; j < 8; j++) {
            int2 v = nb[j];
            tgn[j] = v.x >> 15; ddn[j] = __int_as_float(v.y);
            xsn[j] = nx[j];
          }
#pragma unroll
          for (int j = 0; j < 8; j++) {
            int tg_s = __builtin_amdgcn_readfirstlane(tg[j]);
            edge_step_r1(tg_s, dd[j], xs[j], cur_s, p0, p1, s0, s1, s_xt, s_S, cp,
                         wd0, wd1, uP0, uP1, vP0, vP1, uQ0, uQ1, tile0);
          }
#pragma unroll
          for (int j = 0; j < 8; j++) { tg[j] = tgn[j]; dd[j] = ddn[j]; xs[j] = xsn[j]; }
        }
      }
      if (cur_s >= 0) {
        float* dst = &s_S[(cur_s - tile0) * HN + cp];
        atomicAdd(dst, s0);
        atomicAdd(dst + 1, s1);
      }
    }
  } else {
    if (nchunks > 0) {
      int2* ebuf = (int2*)(s_A + (w * 8) * ASTRIDE);
      {
        int e = wstart + lane;
        int2 v;
        if (e < wend) v = es8[e];
        else { v.x = (int)0xFFFF8000; v.y = 0; }
        ebuf[lane] = v;
      }
      asm volatile("s_waitcnt lgkmcnt(0)" ::: "memory");
      int tg[8]; float dd[8]; unsigned qv[8];
#pragma unroll
      for (int j = 0; j < 8; j++) {
        int2 v = ebuf[j];
        tg[j] = v.x >> 15; dd[j] = __int_as_float(v.y);
        qv[j] = *(const unsigned*)&Q[(size_t)(v.x & 0x7fff) * HN + cp];
      }

      for (int ci = 0; ci < nchunks; ci++) {
        const int2* cb = ebuf + (ci & 1) * 64;
        const int2* nb = ebuf + ((ci + 1) & 1) * 64;
        int2 vnext; vnext.x = (int)0xFFFF8000; vnext.y = 0;
        {
          int e = wstart + (ci + 1) * 64 + lane;
          if (ci + 1 < nchunks && e < wend) vnext = es8[e];
        }
#pragma unroll
        for (int g = 0; g < 7; g++) {
          int tgn[8]; float ddn[8]; unsigned qvn[8];
#pragma unroll
          for (int j = 0; j < 8; j++) {
            int2 v = cb[(g + 1) * 8 + j];
            tgn[j] = v.x >> 15; ddn[j] = __int_as_float(v.y);
            qvn[j] = *(const unsigned*)&Q[(size_t)(v.x & 0x7fff) * HN + cp];
          }
#pragma unroll
          for (int j = 0; j < 8; j++) {
            int tg_s = __builtin_amdgcn_readfirstlane(tg[j]);
            edge_step_lds(tg_s, dd[j], qv[j], cur_s, p0, p1, s0, s1, P, s_S, cp, wd0, wd1, tile0);
          }
#pragma unroll
          for (int j = 0; j < 8; j++) { tg[j] = tgn[j]; dd[j] = ddn[j]; qv[j] = qvn[j]; }
        }
        ebuf[((ci + 1) & 1) * 64 + lane] = vnext;
        asm volatile("s_waitcnt lgkmcnt(0)" ::: "memory");
        {
          int tgn[8]; float ddn[8]; unsigned qvn[8];
#pragma unroll
          for (int j = 0; j < 8; j++) {
            int2 v = nb[j];
            tgn[j] = v.x >> 15; ddn[j] = __int_as_float(v.y);
            qvn[j] = *(const unsigned*)&Q[(size_t)(v.x & 0x7fff) * HN + cp];
          }
#pragma unroll
          for (int j = 0; j < 8; j++) {
            int tg_s = __builtin_amdgcn_readfirstlane(tg[j]);
            edge_step_lds(tg_s, dd[j], qv[j], cur_s, p0, p1, s0, s1, P, s_S, cp, wd0, wd1, tile0);
          }
#pragma unroll
          for (int j = 0; j < 8; j++) { tg[j] = tgn[j]; dd[j] = ddn[j]; qv[j] = qvn[j]; }
        }
      }
      if (cur_s >= 0) {
        float* dst = &s_S[(cur_s - tile0) * HN + cp];
        atomicAdd(dst, s0);
        atomicAdd(dst + 1, s1);
      }
    }
  }
  __syncthreads();  // s_S complete; s_A free for A-tile

  // ================= phase 2: node MLP (quarter-split) =================
  // stage s_S -> s_A bf16: each wave stages 8 rows (rows w*8..w*8+7)
  {
    int srow = w * 8 + (lane >> 3);
    int scol = (lane & 7) * 16;
    const float4* src = (const float4*)&s_S[srow * HN + scol];
    u16* dst = s_A + srow * ASTRIDE + scol;
#pragma unroll
    for (int i = 0; i < 4; i++) {
      float4 v = src[i];
      ushort4 o;
      o.x = f2bf(v.x); o.y = f2bf(v.y); o.z = f2bf(v.z); o.w = f2bf(v.w);
      *(ushort4*)(dst + i * 4) = o;
    }
  }
  __syncthreads();  // cross-wave A reads

  float bb1[4], vcr[4], bb2[4], bbn[4];
#pragma unroll
  for (int ct = 0; ct < 4; ct++) {
    int c = (ch * 4 + ct) * 16 + m16;
    bb1[ct] = b1[c];
    vcr[ct] = vc[c];
    bb2[ct] = b2[c];
    bbn[ct] = FUSE ? b1_next[c] : 0.f;
  }
  int nodem = tile0 + rh * 16 + m16;
  if (nodem >= nnodes) nodem = nnodes - 1;

  f32x4 acc[4];
#pragma unroll
  for (int ct = 0; ct < 4; ct++) acc[ct] = {0.f, 0.f, 0.f, 0.f};
  gemm32_gb(s_A, pwc, rh, ch, quad, m16, acc);         // S@Wc (quarter)

  bf16x8 aH[4];
  if constexpr (RANK1) {
    float xv = s_xt[rh * 16 + m16];
#pragma unroll
    for (int ks = 0; ks < 4; ks++) {
      u16 hv[8];
#pragma unroll
      for (int i = 0; i < 8; i++) {
        int c = ks * 32 + quad * 8 + i;
        hv[i] = f2bf(fmaf(xv, emb_w[c], emb_b[c]));
      }
      aH[ks] = *(bf16x8*)hv;
    }
  } else {
#pragma unroll
    for (int ks = 0; ks < 4; ks++)
      aH[ks] = *(const bf16x8*)&hbf[(size_t)nodem * HN + ks * 32 + quad * 8];
  }
  gemm32_ra_gb(aH, pwn, ch, quad, m16, acc);           // + h@W1a

  // silu(acc + deg*vc + b1) -> own quarter of s_A
  {
    float degv[4];
#pragma unroll
    for (int j = 0; j < 4; j++) {
      int n = tile0 + rh * 16 + quad * 4 + j;
      if (n >= nnodes) n = nnodes - 1;
      degv[j] = (float)deg[n];
    }
#pragma unroll
    for (int ct = 0; ct < 4; ct++)
#pragma unroll
      for (int j = 0; j < 4; j++) {
        int row = rh * 16 + quad * 4 + j;
        float xv = acc[ct][j] + bb1[ct] + degv[j] * vcr[ct];
        s_A[row * ASTRIDE + (ch * 4 + ct) * 16 + m16] = f2bf(silu_f(xv));
      }
  }
  __syncthreads();  // full rows needed by both col-half waves

#pragma unroll
  for (int ct = 0; ct < 4; ct++) acc[ct] = {0.f, 0.f, 0.f, 0.f};
  gemm32_gb(s_A, pwn + 32768, rh, ch, quad, m16, acc); // hidden@W2n

  // h' = acc + b2: store hout quarter; FUSE: also into s_A quarter
#pragma unroll
  for (int ct = 0; ct < 4; ct++)
#pragma unroll
    for (int j = 0; j < 4; j++) {
      int row = rh * 16 + quad * 4 + j;
      int n = tile0 + row;
      u16 hv = f2bf(acc[ct][j] + bb2[ct]);
      if (n < nnodes) hout[(size_t)n * HN + (ch * 4 + ct) * 16 + m16] = hv;
      if (FUSE) s_A[row * ASTRIDE + (ch * 4 + ct) * 16 + m16] = hv;
    }

  if (FUSE) {
    __syncthreads();  // full h' rows for both col-halves
#pragma unroll
    for (int ct = 0; ct < 4; ct++) acc[ct] = {0.f, 0.f, 0.f, 0.f};
    gemm32_gb(s_A, pw_next, rh, ch, quad, m16, acc);   // h'@msgW1a'
#pragma unroll
    for (int ct = 0; ct < 4; ct++)
#pragma unroll
      for (int j = 0; j < 4; j++) {
        int n = tile0 + rh * 16 + quad * 4 + j;
        if (n < nnodes) Pout[(size_t)n * HN + (ch * 4 + ct) * 16 + m16] = f2bf(acc[ct][j] + bbn[ct]);
      }
#pragma unroll
    for (int ct = 0; ct < 4; ct++) acc[ct] = {0.f, 0.f, 0.f, 0.f};
    gemm32_gb(s_A, pw_next + 16384, rh, ch, quad, m16, acc);  // h'@msgW1b'
#pragma unroll
    for (int ct = 0; ct < 4; ct++)
#pragma unroll
      for (int j = 0; j < 4; j++) {
        int n = tile0 + rh * 16 + quad * 4 + j;
        if (n < nnodes) Qout[(size_t)n * HN + (ch * 4 + ct) * 16 + m16] = f2bf(acc[ct][j]);
      }
  }
}

// ---- pool: 469 blocks x 256 thr; thread = (colpair, rowgroup of 16) ----
__global__ __launch_bounds__(256) void pool_kernel(
    const u16* __restrict__ h, const int* __restrict__ batch,
    float* __restrict__ g, int N) {
  __shared__ int s_b[64];
  const int t = threadIdx.x;
  const int n0 = blockIdx.x * 64;
  if (t < 64) {
    int n = n0 + t;
    s_b[t] = (n < N) ? batch[n] : -1;
  }
  __syncthreads();
  const int cp = (t & 63) * 2;
  const int rg = t >> 6;
  int cur = -1;
  float s0 = 0.f, s1 = 0.f;
#pragma unroll 4
  for (int i = 0; i < 16; i++) {
    int r = rg * 16 + i;
    int b = s_b[r];
    if (b < 0) break;  // sorted; -1 only at tail
    if (b != cur) {
      if (cur >= 0) {
        atomicAdd(&g[cur * HN + cp], s0);
        atomicAdd(&g[cur * HN + cp + 1], s1);
      }
      cur = b; s0 = 0.f; s1 = 0.f;
    }
    unsigned v = *(const unsigned*)&h[(size_t)(n0 + r) * HN + cp];
    s0 += bf2f((u16)(v & 0xffffu));
    s1 += bf2f((u16)(v >> 16));
  }
  if (cur >= 0) {
    atomicAdd(&g[cur * HN + cp], s0);
    atomicAdd(&g[cur * HN + cp + 1], s1);
  }
}

// ---- out: one block per graph, split-K halves + shuffle reduce ----
__global__ __launch_bounds__(64) void out_kernel(
    const float* __restrict__ g, const float* __restrict__ w1,
    const float* __restrict__ b1, const float* __restrict__ w2,
    const float* __restrict__ b2, float* __restrict__ out) {
  const int gi = blockIdx.x;
  const int t = threadIdx.x;
  const int c = t & 31, kh = t >> 5;
  float s = 0.f;
  for (int k = kh * 64; k < kh * 64 + 64; k++)
    s += g[gi * HN + k] * w1[k * 32 + c];
  s += __shfl_down(s, 32);
  float r = 0.f;
  if (kh == 0) r = silu_f(s + b1[c]) * w2[c];
  r += __shfl_down(r, 16);
  r += __shfl_down(r, 8);
  r += __shfl_down(r, 4);
  r += __shfl_down(r, 2);
  r += __shfl_down(r, 1);
  if (t == 0) out[gi] = r + b2[0];
}

extern "C" void kernel_launch(void* const* d_in, const int* in_sizes, int n_in,
                              void* d_out, int out_size, void* d_ws, size_t ws_size,
                              hipStream_t stream) {
  const float* x = (const float*)d_in[0];
  const float* pos = (const float*)d_in[1];
  const int* eidx = (const int*)d_in[2];
  const int* batch = (const int*)d_in[3];
  const float* emb_w = (const float*)d_in[4];
  const float* emb_b = (const float*)d_in[5];
  const float* msg_w1 = (const float*)d_in[6];
  const float* msg_b1 = (const float*)d_in[7];
  const float* msg_w2 = (const float*)d_in[8];
  const float* msg_b2 = (const float*)d_in[9];
  const float* node_w1 = (const float*)d_in[10];
  const float* node_b1 = (const float*)d_in[11];
  const float* node_w2 = (const float*)d_in[12];
  const float* node_b2 = (const float*)d_in[13];
  const float* out_w1 = (const float*)d_in[14];
  const float* out_b1 = (const float*)d_in[15];
  const float* out_w2 = (const float*)d_in[16];
  const float* out_b2 = (const float*)d_in[17];
  float* outp = (float*)d_out;

  const int N = 30000, E = 600000, G = 64;
  const size_t NH = (size_t)N * HN;

  u16* hA = (u16*)d_ws;                       // N*128 bf16
  u16* hB = hA + NH;                          // N*128 bf16
  u16* Pa = hB + NH;                          // N*128 bf16 (P ping)
  u16* Qa = Pa + NH;                          // N*128 bf16 (Q ping)
  u16* Pb = Qa + NH;                          // N*128 bf16 (P pong)
  u16* Qb = Pb + NH;                          // N*128 bf16 (Q pong)
  int2* es8 = (int2*)(Qb + NH);               // E int2 (src|tgt<<15, dist)
  int* deg = (int*)(es8 + E);                 // N
  int* off = deg + N;                         // N (block-local exclusive)
  int* bsum = off + N;                        // 128 (scanned block sums)
  float* g = (float*)(bsum + 128);            // 64*128 f32
  u16* pw = (u16*)(g + G * HN);               // 4*6*16384 bf16
  u16* pwc = pw + (size_t)4 * 6 * 16384;      // 4*16384 bf16 (folded Wc)
  float* vcb = (float*)(pwc + (size_t)4 * 16384);  // 4*128 f32
  float* uvb = vcb + 4 * 128;                 // 3*128 f32 (layer-0 rank-1 vecs)
  int* rnk = (int*)Pb;                        // E ints, aliases P-pong (dead before layer0)

  const int NB = (N + 255) / 256;
  const int NLB = (N + LTM - 1) / LTM;

  // pack + zero deg/g (replaces memsets)
  pack_weights<<<(4 * 6 * 16384 + 255) / 256, 256, 0, stream>>>(
      msg_w1, msg_w2, node_w1, node_w2, pw, deg, g, N, G * HN);
  fold_kernel<<<8, 256, 0, stream>>>(msg_w2, node_w1, msg_b2, pw, pwc, vcb,
                                     msg_w1, emb_w, emb_b, msg_b1, uvb);

  // counting sort by target (rank precomputed in hist -> atomic-free scatter;
  // scan3 folded into scatter/layer via off+bsum addressing)
  hist_kernel<<<(E + 255) / 256, 256, 0, stream>>>(eidx, deg, rnk, E);
  scan1_kernel<<<NB, 256, 0, stream>>>(deg, off, bsum, N);
  scan2_kernel<<<1, 256, 0, stream>>>(bsum, NB);
  scatter_kernel<<<(E + 255) / 256, 256, 0, stream>>>(eidx, pos, off, bsum, rnk, es8, E);

  // NOTE: no proj kernel — layer 0 uses the rank-1 path (h0 = x*emb_w + emb_b)

  for (int l = 0; l < 4; l++) {
    const u16* pwl = pw + (size_t)(l * 6) * 16384;
    const float* w1d = msg_w1 + (size_t)(l * 257 + 256) * 128;
    u16* hin = (l & 1) ? hA : hB;   // l0: unused
    u16* hot = (l & 1) ? hB : hA;   // l0->hA, l1->hB, l2->hA, l3->hB
    u16* Pin = (l & 1) ? Pb : Pa;   // l1 reads Pb (l0 out), l2 reads Pa, l3 reads Pb
    u16* Qin = (l & 1) ? Qb : Qa;
    u16* Pot = (l & 1) ? Pa : Pb;
    u16* Qot = (l & 1) ? Qa : Qb;
    if (l == 0) {
      layer_kernel<true, true><<<NLB, 256, 0, stream>>>(
          Pin, Qin, hin, hot, off, bsum, deg, w1d, es8,
          pwc + (size_t)l * 16384, vcb + l * 128,
          pwl + 3 * 16384, node_b1 + l * 128, node_b2 + l * 128,
          pw + (size_t)((l + 1) * 6) * 16384, msg_b1 + (l + 1) * 128, Pot, Qot,
          x, uvb, emb_w, emb_b, N, E);
    } else if (l < 3) {
      layer_kernel<true, false><<<NLB, 256, 0, stream>>>(
          Pin, Qin, hin, hot, off, bsum, deg, w1d, es8,
          pwc + (size_t)l * 16384, vcb + l * 128,
          pwl + 3 * 16384, node_b1 + l * 128, node_b2 + l * 128,
          pw + (size_t)((l + 1) * 6) * 16384, msg_b1 + (l + 1) * 128, Pot, Qot,
          x, uvb, emb_w, emb_b, N, E);
    } else {
      layer_kernel<false, false><<<NLB, 256, 0, stream>>>(
          Pin, Qin, hin, hot, off, bsum, deg, w1d, es8,
          pwc + (size_t)l * 16384, vcb + l * 128,
          pwl + 3 * 16384, node_b1 + l * 128, node_b2 + l * 128,
          nullptr, nullptr, nullptr, nullptr,
          x, uvb, emb_w, emb_b, N, E);
    }
  }

  pool_kernel<<<(N + 63) / 64, 256, 0, stream>>>(hB, batch, g, N);
  out_kernel<<<G, 64, 0, stream>>>(g, out_w1, out_b1, out_w2, out_b2, outp);
}